// Round 1
// baseline (1795.949 us; speedup 1.0000x reference)
//
#include <hip/hip_runtime.h>
#include <hip/hip_bf16.h>
#include <cstdint>
#include <cstddef>

typedef _Float16 f16;
typedef _Float16 f16x8 __attribute__((ext_vector_type(8)));
typedef _Float16 f16x4 __attribute__((ext_vector_type(4)));
typedef float f32x4 __attribute__((ext_vector_type(4)));
typedef unsigned long long u64;
typedef unsigned int u32;
typedef unsigned int u32x4 __attribute__((ext_vector_type(4)));

#define B_   256
#define T_   512
#define V_   50000
#define D_   256
#define H_   256
#define A_   128
#define N4H  1024

__device__ __forceinline__ float sigmoid_f(float x) {
    return __builtin_amdgcn_rcpf(1.f + __expf(-x));
}
__device__ __forceinline__ float tanh_f(float x) {
    float e = __expf(-2.f * fabsf(x));
    float t = 1.f - 2.f * e * __builtin_amdgcn_rcpf(1.f + e);
    return copysignf(t, x);
}

// asm MFMA with B operand taken straight from AGPRs (no accvgpr_read moves)
#define MFMA_A(accv, afragv, bfraga)                                         \
    asm volatile("v_mfma_f32_16x16x32_f16 %0, %1, %2, %0"                    \
                 : "+v"(accv) : "v"(afragv), "a"(bfraga))

// ---------------------------------------------------------------------------
// K0: weight transpose + fp32->fp16 cast.
// ---------------------------------------------------------------------------
__global__ __launch_bounds__(256) void k0_convert(
    const float* __restrict__ lstm_kernel, const float* __restrict__ w_omega,
    f16* __restrict__ WxT, f16* __restrict__ WhT, f16* __restrict__ WomT) {
    int blk = blockIdx.x;
    int tau = threadIdx.x;  // 0..255 (= k / h index)
    if (blk < N4H) {
        int n = blk;
        WxT[n * 256 + tau] = (f16)lstm_kernel[(size_t)tau * N4H + n];
        WhT[n * 256 + tau] = (f16)lstm_kernel[(size_t)(256 + tau) * N4H + n];
    } else {
        int a = blk - N4H;  // 0..127
        WomT[a * 256 + tau] = (f16)w_omega[(size_t)tau * A_ + a];
    }
}

// ---------------------------------------------------------------------------
// K1: seq_len[b] = sum_t (x[b,t] != 0)
// ---------------------------------------------------------------------------
__global__ __launch_bounds__(256) void k1_seqlen(
    const int* __restrict__ x, int* __restrict__ seqlen) {
    __shared__ int red[256];
    int b = blockIdx.x, tau = threadIdx.x;
    int cnt = (x[b * T_ + tau] != 0) + (x[b * T_ + tau + 256] != 0);
    red[tau] = cnt;
    __syncthreads();
    for (int s = 128; s > 0; s >>= 1) {
        if (tau < s) red[tau] += red[tau + s];
        __syncthreads();
    }
    if (tau == 0) seqlen[b] = red[0];
}

// ---------------------------------------------------------------------------
// K2: Zx = embed[x] @ Wx + bias, fp16.  Column layout is half-split AND
// gate-interleaved: n = g*256 + half*128 + colu  ->  n'' = half*512 + colu*4 + g
// so k3 reads {i,j,f,o} for one unit as ONE ds_read_b64.
// ---------------------------------------------------------------------------
__global__ __launch_bounds__(256) void k2_zx(
    const int* __restrict__ x, const float* __restrict__ embed,
    const f16* __restrict__ WxT, const float* __restrict__ bias,
    f16* __restrict__ Zx, int t0, int Tc) {
    __shared__ __align__(16) f16 A_s[64][264];   // [m][k], pad 8
    __shared__ __align__(16) f16 B_s[128][72];   // [n][k-slice], pad 8
    __shared__ int tok_s[64];

    int tau  = threadIdx.x;
    int bm   = blockIdx.x;
    int i0   = bm * 64;
    int wave = tau >> 6, lane = tau & 63;
    int q = lane >> 4, c = lane & 15;

    if (tau < 64) {
        int i  = i0 + tau;
        int bb = i / Tc, tr = i - bb * Tc;
        tok_s[tau] = x[bb * T_ + t0 + tr];
    }
    __syncthreads();

    // gather A: 64 rows x 256 f32 -> fp16 LDS. 4 threads/row, 16 float4 each.
    {
        int r = tau >> 2, quarter = tau & 3;
        const float4* src =
            (const float4*)(embed + (size_t)tok_s[r] * D_ + quarter * 64);
        f16* dst = &A_s[r][quarter * 64];
#pragma unroll
        for (int j = 0; j < 16; j++) {
            float4 v = src[j];
            dst[j * 4 + 0] = (f16)v.x;
            dst[j * 4 + 1] = (f16)v.y;
            dst[j * 4 + 2] = (f16)v.z;
            dst[j * 4 + 3] = (f16)v.w;
        }
    }

    for (int np = 0; np < 8; np++) {
        f32x4 acc[8];
#pragma unroll
        for (int ni = 0; ni < 8; ni++) acc[ni] = (f32x4){0.f, 0.f, 0.f, 0.f};

        for (int kt = 0; kt < 4; kt++) {
            __syncthreads();  // previous B_s consumers done
            {
                int n = tau >> 1, half = tau & 1;
                const f16x8* src = (const f16x8*)(WxT +
                    (size_t)(np * 128 + n) * 256 + kt * 64 + half * 32);
                f16x8* dst = (f16x8*)&B_s[n][half * 32];
#pragma unroll
                for (int j = 0; j < 4; j++) dst[j] = src[j];
            }
            __syncthreads();
#pragma unroll
            for (int s = 0; s < 2; s++) {
                f16x8 afrag =
                    *(const f16x8*)&A_s[wave * 16 + c][kt * 64 + s * 32 + q * 8];
#pragma unroll
                for (int ni = 0; ni < 8; ni++) {
                    f16x8 bfrag = *(const f16x8*)&B_s[ni * 16 + c][s * 32 + q * 8];
                    acc[ni] = __builtin_amdgcn_mfma_f32_16x16x32_f16(
                        afrag, bfrag, acc[ni], 0, 0, 0);
                }
            }
        }
        // epilogue (half-split + gate-interleaved column write)
#pragma unroll
        for (int ni = 0; ni < 8; ni++) {
            int n    = np * 128 + ni * 16 + c;
            int g    = n >> 8, rem = n & 255;
            int half = rem >> 7, colu = rem & 127;
            int np2  = half * 512 + colu * 4 + g;
            float bv = bias[n];
#pragma unroll
            for (int r = 0; r < 4; r++) {
                int row = i0 + wave * 16 + q * 4 + r;
                Zx[(size_t)row * N4H + np2] = (f16)(acc[ni][r] + bv);
            }
        }
    }
}

// ---------------------------------------------------------------------------
// K3: persistent LSTM, split-K pipelined pair exchange.
// 32 WGs x 512 thr. PAIRING IS XCD-AWARE: partner = wgid ^ 8, which under the
// empirical round-robin block->XCD mapping (bid%8 = XCD) lands both halves of
// a pair on the SAME XCD so the exchange can be served by the shared L2.
//   pair = (wgid&7) | ((wgid>>4)<<3)  in 0..15, half = (wgid>>3)&1.
// DUAL-PUBLISH exchange:
//   fast buffer (Hexf): plain store -> dirty line in local L2; partner polls
//     with an inline-asm sc0 load (L1-bypass, L2-hit, ~200cy when co-resident)
//   slow buffer (Hex):  agent-scope atomic store/load through the coherence
//     point, exactly the old path. Poll falls back to it after 4 failed fast
//     spins, so correctness NEVER depends on the XCD mapping (slow buffer is
//     only ever touched by agent-scope ops -> can't hide in a remote L2).
// Every word self-validates: word = (tag16 << 16) | h16, tag = (t+1)&0xffff.
// Zx prefetch is issued AFTER the poll (the spin's vmcnt(0) would drain it);
// its HBM latency hides under barrier + partner-half MFMA + gates.
// ---------------------------------------------------------------------------
__global__ __launch_bounds__(512, 2) void k3_lstm(
    const f16* __restrict__ Zx, const f16* __restrict__ WhT,
    const int* __restrict__ seqlen, f16* __restrict__ outs,
    f16* __restrict__ Hstate, float* __restrict__ Cstate,
    u32* __restrict__ Hex, u32* __restrict__ Hexf,
    int t0, int Tc, int first, int last) {
    __shared__ __align__(16) f16 Zx_s[2][16][520];  // [parity][row][512 cols]
    __shared__ __align__(16) f16 h_s[2][16][264];   // [parity][row][k]

    int tau  = threadIdx.x;
    int w    = tau >> 6, lane = tau & 63;
    int q = lane >> 4, c = lane & 15;
    int wgid = blockIdx.x;
    int pair = (wgid & 7) | ((wgid >> 4) << 3);  // 0..15
    int half = (wgid >> 3) & 1;                  // partner = wgid ^ 8
    int b0 = pair * 16;
    int u0 = half * 128, pu0 = (half ^ 1) * 128;
    int u  = u0 + w * 16 + c;   // this lane's hidden unit
    int col = w * 16 + c;       // unit index inside our 128-chunk

    u32*       hexS_my = Hex  + (size_t)wgid * 2 * 2048;       // [parity][16][128]
    const u32* hexS_pr = Hex  + (size_t)(wgid ^ 8) * 2 * 2048;
    u32*       hexF_my = Hexf + (size_t)wgid * 2 * 2048;
    const u32* hexF_pr = Hexf + (size_t)(wgid ^ 8) * 2 * 2048;

    // ---- Wh fragments pinned in AGPRs; slot s<4 = own-half K, s>=4 partner ----
    f32x4 wha[4][8];
#pragma unroll
    for (int g = 0; g < 4; g++)
#pragma unroll
        for (int s = 0; s < 8; s++) {
            int kc = (s < 4) ? (half * 4 + s) : ((half ^ 1) * 4 + (s - 4));
            f16x8 f = *(const f16x8*)(WhT +
                (size_t)(g * 256 + u0 + w * 16 + c) * 256 + kc * 32 + q * 8);
            f32x4 t = __builtin_bit_cast(f32x4, f);
            asm volatile("" : "=a"(wha[g][s]) : "0"(t));
        }

    // k-element offsets within an h_s row for the two K-halves
    int kOwn = half * 128 + q * 8;          // + kk*32
    int kPar = (half ^ 1) * 128 + q * 8;

    // ---- init h_s / cst / hprev ----
    int p0 = t0 & 1;
    if (first) {
        for (int idx = tau; idx < 2 * 16 * 264; idx += 512)
            ((f16*)h_s)[idx] = (f16)0.f;
    } else {
        for (int idx = tau; idx < 16 * 256; idx += 512) {
            int r = idx >> 8, k = idx & 255;
            h_s[p0][r][k] = Hstate[(b0 + r) * H_ + k];
        }
    }

    float cst[4];
    f16   hprev[4];
    int   sl[4];
#pragma unroll
    for (int r = 0; r < 4; r++) {
        int row = q * 4 + r;
        cst[r]   = first ? 0.f : Cstate[(b0 + row) * H_ + u];
        hprev[r] = first ? (f16)0.f : Hstate[(b0 + row) * H_ + u];
        sl[r]    = seqlen[b0 + row];
    }

    // Zx staging geometry: thread stages 32 B of row (tau>>5), cols (tau&31)*16
    int r_st = tau >> 5;
    int cc   = (tau & 31) * 16;
    const f16* zxrow = Zx + ((size_t)(b0 + r_st) * Tc) * N4H + half * 512 + cc;

    // prologue: fill Zx_s for step 0
    {
        const f16x8* src = (const f16x8*)zxrow;
        f16x8* dst = (f16x8*)&Zx_s[p0][r_st][cc];
        dst[0] = src[0];
        dst[1] = src[1];
    }
    // partner-merge geometry: thread handles 4 words: row tau>>5, cols (tau&31)*4
    int rr = tau >> 5;
    int uu = (tau & 31) * 4;

    __syncthreads();

    // prologue: own-half partial MFMA from h_s[p0]
    f32x4 accO[4];
#pragma unroll
    for (int g = 0; g < 4; g++) accO[g] = (f32x4){0.f, 0.f, 0.f, 0.f};
#pragma unroll
    for (int kk = 0; kk < 4; kk++) {
        f16x8 afrag = *(const f16x8*)&h_s[p0][c][kOwn + kk * 32];
#pragma unroll
        for (int g = 0; g < 4; g++) MFMA_A(accO[g], afrag, wha[g][kk]);
    }

    for (int tt = 0; tt < Tc; tt++) {
        int t   = t0 + tt;
        int cur = t & 1, nxt = cur ^ 1;

        // poll + merge partner half of h_t (skip at chunk start: h_s complete)
        if (tt > 0) {
            u32 tagp = (u32)(t & 0xffff);
            const u32* fp = hexF_pr + cur * 2048 + rr * 128 + uu;  // 16B aligned
            const u64* sp = (const u64*)(hexS_pr + cur * 2048 + rr * 128 + uu);
            u64 hw;
            int tries = 0;
            for (;;) {
                u32x4 fv;
                // L1-bypass, L2-hit poll of the fast buffer
                asm volatile("global_load_dwordx4 %0, %1, off sc0\n\t"
                             "s_waitcnt vmcnt(0)"
                             : "=&v"(fv) : "v"(fp) : "memory");
                if ((fv.x >> 16) == tagp && (fv.y >> 16) == tagp &&
                    (fv.z >> 16) == tagp && (fv.w >> 16) == tagp) {
                    hw = (u64)(fv.x & 0xffffu) | ((u64)(fv.y & 0xffffu) << 16) |
                         ((u64)(fv.z & 0xffffu) << 32) |
                         ((u64)(fv.w & 0xffffu) << 48);
                    break;
                }
                if (++tries > 4) {  // fallback: coherence-point copy
                    u64 s0 = __hip_atomic_load(sp + 0, __ATOMIC_RELAXED,
                                               __HIP_MEMORY_SCOPE_AGENT);
                    u64 s1 = __hip_atomic_load(sp + 1, __ATOMIC_RELAXED,
                                               __HIP_MEMORY_SCOPE_AGENT);
                    if (((u32)(s0 >> 16) & 0xffffu) == tagp &&
                        ((u32)(s0 >> 48)) == tagp &&
                        ((u32)(s1 >> 16) & 0xffffu) == tagp &&
                        ((u32)(s1 >> 48)) == tagp) {
                        hw = (s0 & 0xffff) | (((s0 >> 32) & 0xffff) << 16) |
                             ((s1 & 0xffff) << 32) | (((s1 >> 32) & 0xffff) << 48);
                        break;
                    }
                }
            }
            *(u64*)&h_s[cur][rr][pu0 + uu] = hw;
        }

        // Zx prefetch for t+1 — issued AFTER the poll so the spin's vmcnt(0)
        // can't drain it; latency hides under barrier + MFMA + gates.
        int tn = (tt + 1 < Tc) ? tt + 1 : tt;
        const f16x8* psrc = (const f16x8*)(zxrow + (size_t)tn * N4H);
        f16x8 z0 = psrc[0];
        f16x8 z1 = psrc[1];

        __syncthreads();  // partner half visible; h_s[cur] complete

        // partner-half K MFMA (slots 4-7) -> full pre-activations in accO
#pragma unroll
        for (int kk = 0; kk < 4; kk++) {
            f16x8 afrag = *(const f16x8*)&h_s[cur][c][kPar + kk * 32];
#pragma unroll
            for (int g = 0; g < 4; g++) MFMA_A(accO[g], afrag, wha[g][4 + kk]);
        }

        // gates (C layout: col=c, row=q*4+r); dual-publish own h with tag t+1
        u32 tag = (u32)((t + 1) & 0xffff);
        f16 ovals[4];
#pragma unroll
        for (int r = 0; r < 4; r++) {
            int row = q * 4 + r;
            f16x4 zv = *(const f16x4*)&Zx_s[cur][row][col * 4];
            float zi = accO[0][r] + (float)zv[0];
            float zj = accO[1][r] + (float)zv[1];
            float zf = accO[2][r] + (float)zv[2];
            float zo = accO[3][r] + (float)zv[3];
            float ig = sigmoid_f(zi);
            float jg = tanh_f(zj);
            float fg = sigmoid_f(zf + 1.f);
            float og = sigmoid_f(zo);
            float cn = cst[r] * fg + ig * jg;
            float hn = tanh_f(cn) * og;
            bool  m  = (t < sl[r]);
            cst[r]   = m ? cn : cst[r];
            f16 hkeep = m ? (f16)hn : hprev[r];
            hprev[r]  = hkeep;
            h_s[nxt][row][u] = hkeep;
            u32 word = (tag << 16) |
                       (u32)(unsigned short)__builtin_bit_cast(short, hkeep);
            hexF_my[nxt * 2048 + row * 128 + col] = word;  // fast: local L2
            __hip_atomic_store(&hexS_my[nxt * 2048 + row * 128 + col], word,
                               __ATOMIC_RELAXED, __HIP_MEMORY_SCOPE_AGENT);
            ovals[r] = m ? (f16)hn : (f16)0.f;
        }

        // consume Zx prefetch into other parity
        {
            f16x8* dst = (f16x8*)&Zx_s[nxt][r_st][cc];
            dst[0] = z0;
            dst[1] = z1;
        }

        // outs stores
#pragma unroll
        for (int r = 0; r < 4; r++)
            outs[((size_t)(b0 + q * 4 + r) * T_ + t) * H_ + u] = ovals[r];

        __syncthreads();  // own half of h_s[nxt] + Zx_s[nxt] ready

        // own-half K MFMA for step t+1 (slots 0-3) — covers exchange latency
#pragma unroll
        for (int g = 0; g < 4; g++) accO[g] = (f32x4){0.f, 0.f, 0.f, 0.f};
#pragma unroll
        for (int kk = 0; kk < 4; kk++) {
            f16x8 afrag = *(const f16x8*)&h_s[nxt][c][kOwn + kk * 32];
#pragma unroll
            for (int g = 0; g < 4; g++) MFMA_A(accO[g], afrag, wha[g][kk]);
        }
    }

    if (!last) {
        int parity = (t0 + Tc) & 1;
        for (int idx = tau; idx < 16 * 128; idx += 512) {
            int r = idx >> 7, k = u0 + (idx & 127);
            Hstate[(b0 + r) * H_ + k] = h_s[parity][r][k];
        }
#pragma unroll
        for (int r = 0; r < 4; r++)
            Cstate[(b0 + q * 4 + r) * H_ + u] = cst[r];
    }
}

// ---------------------------------------------------------------------------
// K4: attention + head. One WG (256 thr) per batch row.
// ---------------------------------------------------------------------------
__global__ __launch_bounds__(256) void k4_attn(
    const f16* __restrict__ outs, const f16* __restrict__ WomT,
    const float* __restrict__ b_omega, const float* __restrict__ u_omega,
    const float* __restrict__ w, const float* __restrict__ bfin,
    float* __restrict__ out) {
    __shared__ __align__(16) f16 A_s[64][264];
    __shared__ __align__(16) f16 val_s[64][132];
    __shared__ float u_s[128];
    __shared__ float vu_s[512];
    __shared__ float red0[256], red1[256];

    int b = blockIdx.x, tau = threadIdx.x;
    int wave = tau >> 6, lane = tau & 63;
    int q = lane >> 4, c = lane & 15;

    if (tau < 128) u_s[tau] = u_omega[tau];
    float bom[8];
#pragma unroll
    for (int ni = 0; ni < 8; ni++) bom[ni] = b_omega[ni * 16 + c];

    for (int ch = 0; ch < 8; ch++) {
        int t0c = ch * 64;
        __syncthreads();  // protects A_s/val_s reuse (+ covers u_s init)
        {   // stage 64 rows of outs
            int r = tau >> 2, seg = tau & 3;
            const f16x8* src =
                (const f16x8*)(outs + ((size_t)b * T_ + t0c + r) * H_ + seg * 64);
            f16x8* dst = (f16x8*)&A_s[r][seg * 64];
#pragma unroll
            for (int j = 0; j < 8; j++) dst[j] = src[j];
        }
        __syncthreads();

        f32x4 acc[8];
#pragma unroll
        for (int ni = 0; ni < 8; ni++) acc[ni] = (f32x4){0.f, 0.f, 0.f, 0.f};
#pragma unroll
        for (int kc = 0; kc < 8; kc++) {
            f16x8 afrag = *(const f16x8*)&A_s[wave * 16 + c][kc * 32 + q * 8];
#pragma unroll
            for (int ni = 0; ni < 8; ni++) {
                f16x8 bfrag = *(const f16x8*)(WomT +
                    (size_t)(ni * 16 + c) * 256 + kc * 32 + q * 8);
                acc[ni] = __builtin_amdgcn_mfma_f32_16x16x32_f16(
                    afrag, bfrag, acc[ni], 0, 0, 0);
            }
        }
#pragma unroll
        for (int ni = 0; ni < 8; ni++) {
#pragma unroll
            for (int r = 0; r < 4; r++) {
                val_s[wave * 16 + q * 4 + r][ni * 16 + c] =
                    (f16)tanh_f(acc[ni][r] + bom[ni]);
            }
        }
        __syncthreads();
        if (tau < 64) {
            float s = 0.f;
#pragma unroll 8
            for (int a = 0; a < 128; a++) s += (float)val_s[tau][a] * u_s[a];
            vu_s[t0c + tau] = s;
        }
    }
    __syncthreads();

    // softmax over T=512
    red0[tau] = fmaxf(vu_s[tau], vu_s[tau + 256]);
    __syncthreads();
    for (int s = 128; s > 0; s >>= 1) {
        if (tau < s) red0[tau] = fmaxf(red0[tau], red0[tau + s]);
        __syncthreads();
    }
    float mx = red0[0];
    __syncthreads();
    float e0 = __expf(vu_s[tau] - mx), e1 = __expf(vu_s[tau + 256] - mx);
    red0[tau] = e0 + e1;
    __syncthreads();
    for (int s = 128; s > 0; s >>= 1) {
        if (tau < s) red0[tau] += red0[tau + s];
        __syncthreads();
    }
    float inv = 1.f / red0[0];
    __syncthreads();
    vu_s[tau]       = e0 * inv;
    vu_s[tau + 256] = e1 * inv;
    __syncthreads();

    // last[h] = sum_t alpha[t] * outs[b][t][h]   (tau = h)
    float lastv = 0.f;
#pragma unroll 4
    for (int t = 0; t < T_; t++)
        lastv += vu_s[t] * (float)outs[((size_t)b * T_ + t) * H_ + tau];

    // logits + 2-class softmax
    red0[tau] = lastv * w[tau * 2 + 0];
    red1[tau] = lastv * w[tau * 2 + 1];
    __syncthreads();
    for (int s = 128; s > 0; s >>= 1) {
        if (tau < s) {
            red0[tau] += red0[tau + s];
            red1[tau] += red1[tau + s];
        }
        __syncthreads();
    }
    if (tau == 0) {
        float l0 = red0[0] + bfin[0], l1 = red1[0] + bfin[1];
        float mm = fmaxf(l0, l1);
        float a0 = __expf(l0 - mm), a1 = __expf(l1 - mm);
        float den = a0 + a1;
        out[b * 2 + 0] = a0 / den;
        out[b * 2 + 1] = a1 / den;
    }
}

// ---------------------------------------------------------------------------
extern "C" void kernel_launch(void* const* d_in, const int* in_sizes, int n_in,
                              void* d_out, int out_size, void* d_ws,
                              size_t ws_size, hipStream_t stream) {
    const int*   x           = (const int*)d_in[0];
    const float* embed       = (const float*)d_in[1];
    const float* lstm_kernel = (const float*)d_in[2];
    const float* lstm_bias   = (const float*)d_in[3];
    const float* w_omega     = (const float*)d_in[4];
    const float* b_omega     = (const float*)d_in[5];
    const float* u_omega     = (const float*)d_in[6];
    const float* w           = (const float*)d_in[7];
    const float* bfin        = (const float*)d_in[8];
    float*       out         = (float*)d_out;

    char* ws = (char*)d_ws;
    f16*   WxT    = (f16*)(ws + 0);              //  524288 B
    f16*   WhT    = (f16*)(ws + 524288);         //  524288 B
    f16*   WomT   = (f16*)(ws + 1048576);        //   65536 B
    int*   seqlen = (int*)(ws + 1114112);        //    1024 B
    f16*   Hstate = (f16*)(ws + 1115136);        //  131072 B
    float* Cstate = (float*)(ws + 1246208);      //  262144 B
    u32*   Hex    = (u32*)(ws + 1508352);        //  524288 B (slow/agent copy)
    u32*   Hexf   = (u32*)(ws + 2032640);        //  524288 B (fast/L2 copy)
    f16*   outs   = (f16*)(ws + 2556928);        // 67108864 B
    f16*   Zx     = (f16*)(ws + 2556928 + 67108864);

    const size_t fixed = 2556928ull + 67108864ull;
    int nch = 1;
    while (nch < 16 && fixed + 268435456ull / (size_t)nch > ws_size) nch <<= 1;
    int Tc = T_ / nch;

    k0_convert<<<1152, 256, 0, stream>>>(lstm_kernel, w_omega, WxT, WhT, WomT);
    k1_seqlen<<<256, 256, 0, stream>>>(x, seqlen);
    for (int chk = 0; chk < nch; chk++) {
        int t0 = chk * Tc;
        k2_zx<<<(B_ * Tc) / 64, 256, 0, stream>>>(x, embed, WxT, lstm_bias, Zx,
                                                  t0, Tc);
        k3_lstm<<<32, 512, 0, stream>>>(Zx, WhT, seqlen, outs, Hstate, Cstate,
                                        Hex, Hexf, t0, Tc, chk == 0 ? 1 : 0,
                                        chk == nch - 1 ? 1 : 0);
    }
    k4_attn<<<256, 256, 0, stream>>>(outs, WomT, b_omega, u_omega, w, bfin, out);
}

// Round 4
// 1584.730 us; speedup vs baseline: 1.1333x; 1.1333x over previous
//
#include <hip/hip_runtime.h>
#include <hip/hip_bf16.h>
#include <cstdint>
#include <cstddef>

typedef _Float16 f16;
typedef _Float16 f16x8 __attribute__((ext_vector_type(8)));
typedef _Float16 f16x4 __attribute__((ext_vector_type(4)));
typedef float f32x4 __attribute__((ext_vector_type(4)));
typedef unsigned long long u64;
typedef unsigned int u32;

#define B_   256
#define T_   512
#define V_   50000
#define D_   256
#define H_   256
#define A_   128
#define N4H  1024

__device__ __forceinline__ float sigmoid_f(float x) {
    return __builtin_amdgcn_rcpf(1.f + __expf(-x));
}
__device__ __forceinline__ float tanh_f(float x) {
    float e = __expf(-2.f * fabsf(x));
    float t = 1.f - 2.f * e * __builtin_amdgcn_rcpf(1.f + e);
    return copysignf(t, x);
}

// asm MFMA with B operand taken straight from AGPRs (no accvgpr_read moves)
#define MFMA_A(accv, afragv, bfraga)                                         \
    asm volatile("v_mfma_f32_16x16x32_f16 %0, %1, %2, %0"                    \
                 : "+v"(accv) : "v"(afragv), "a"(bfraga))

// LDS-drain-only barrier: __syncthreads emits s_waitcnt vmcnt(0) lgkmcnt(0)
// before s_barrier; the vmcnt(0) drains z-prefetch loads issued ~50cy earlier
// (~800cy exposed) at barrier 1 and the in-flight partner polls (~500cy) at
// barrier 2 — none of which any consumer needs drained (compiler inserts its
// own waits for its own loads before their uses). Only LDS ordering is needed
// at these barriers. sched_barrier(0) on both sides pins producer stores
// below the waitcnt and blocks ds_read hoisting above the barrier.
#define LGKM_BARRIER()                                                       \
    do {                                                                     \
        asm volatile("s_waitcnt lgkmcnt(0)" ::: "memory");                   \
        __builtin_amdgcn_sched_barrier(0);                                   \
        __builtin_amdgcn_s_barrier();                                        \
        __builtin_amdgcn_sched_barrier(0);                                   \
    } while (0)

// ---------------------------------------------------------------------------
// K0: weight transpose + fp32->fp16 cast.
// ---------------------------------------------------------------------------
__global__ __launch_bounds__(256) void k0_convert(
    const float* __restrict__ lstm_kernel, const float* __restrict__ w_omega,
    f16* __restrict__ WxT, f16* __restrict__ WhT, f16* __restrict__ WomT) {
    int blk = blockIdx.x;
    int tau = threadIdx.x;  // 0..255 (= k / h index)
    if (blk < N4H) {
        int n = blk;
        WxT[n * 256 + tau] = (f16)lstm_kernel[(size_t)tau * N4H + n];
        WhT[n * 256 + tau] = (f16)lstm_kernel[(size_t)(256 + tau) * N4H + n];
    } else {
        int a = blk - N4H;  // 0..127
        WomT[a * 256 + tau] = (f16)w_omega[(size_t)tau * A_ + a];
    }
}

// ---------------------------------------------------------------------------
// K1: seq_len[b] = sum_t (x[b,t] != 0)
// ---------------------------------------------------------------------------
__global__ __launch_bounds__(256) void k1_seqlen(
    const int* __restrict__ x, int* __restrict__ seqlen) {
    __shared__ int red[256];
    int b = blockIdx.x, tau = threadIdx.x;
    int cnt = (x[b * T_ + tau] != 0) + (x[b * T_ + tau + 256] != 0);
    red[tau] = cnt;
    __syncthreads();
    for (int s = 128; s > 0; s >>= 1) {
        if (tau < s) red[tau] += red[tau + s];
        __syncthreads();
    }
    if (tau == 0) seqlen[b] = red[0];
}

// ---------------------------------------------------------------------------
// K2: Zx = embed[x] @ Wx + bias, fp16.  Column layout is half-split AND
// gate-interleaved: n = g*256 + half*128 + colu  ->  n'' = half*512 + colu*4 + g
// so k3 reads {i,j,f,o} for one unit as ONE ds_read_b64.
// ---------------------------------------------------------------------------
__global__ __launch_bounds__(256) void k2_zx(
    const int* __restrict__ x, const float* __restrict__ embed,
    const f16* __restrict__ WxT, const float* __restrict__ bias,
    f16* __restrict__ Zx, int t0, int Tc) {
    __shared__ __align__(16) f16 A_s[64][264];   // [m][k], pad 8
    __shared__ __align__(16) f16 B_s[128][72];   // [n][k-slice], pad 8
    __shared__ int tok_s[64];

    int tau  = threadIdx.x;
    int bm   = blockIdx.x;
    int i0   = bm * 64;
    int wave = tau >> 6, lane = tau & 63;
    int q = lane >> 4, c = lane & 15;

    if (tau < 64) {
        int i  = i0 + tau;
        int bb = i / Tc, tr = i - bb * Tc;
        tok_s[tau] = x[bb * T_ + t0 + tr];
    }
    __syncthreads();

    // gather A: 64 rows x 256 f32 -> fp16 LDS. 4 threads/row, 16 float4 each.
    {
        int r = tau >> 2, quarter = tau & 3;
        const float4* src =
            (const float4*)(embed + (size_t)tok_s[r] * D_ + quarter * 64);
        f16* dst = &A_s[r][quarter * 64];
#pragma unroll
        for (int j = 0; j < 16; j++) {
            float4 v = src[j];
            dst[j * 4 + 0] = (f16)v.x;
            dst[j * 4 + 1] = (f16)v.y;
            dst[j * 4 + 2] = (f16)v.z;
            dst[j * 4 + 3] = (f16)v.w;
        }
    }

    for (int np = 0; np < 8; np++) {
        f32x4 acc[8];
#pragma unroll
        for (int ni = 0; ni < 8; ni++) acc[ni] = (f32x4){0.f, 0.f, 0.f, 0.f};

        for (int kt = 0; kt < 4; kt++) {
            __syncthreads();  // previous B_s consumers done
            {
                int n = tau >> 1, half = tau & 1;
                const f16x8* src = (const f16x8*)(WxT +
                    (size_t)(np * 128 + n) * 256 + kt * 64 + half * 32);
                f16x8* dst = (f16x8*)&B_s[n][half * 32];
#pragma unroll
                for (int j = 0; j < 4; j++) dst[j] = src[j];
            }
            __syncthreads();
#pragma unroll
            for (int s = 0; s < 2; s++) {
                f16x8 afrag =
                    *(const f16x8*)&A_s[wave * 16 + c][kt * 64 + s * 32 + q * 8];
#pragma unroll
                for (int ni = 0; ni < 8; ni++) {
                    f16x8 bfrag = *(const f16x8*)&B_s[ni * 16 + c][s * 32 + q * 8];
                    acc[ni] = __builtin_amdgcn_mfma_f32_16x16x32_f16(
                        afrag, bfrag, acc[ni], 0, 0, 0);
                }
            }
        }
        // epilogue (half-split + gate-interleaved column write)
#pragma unroll
        for (int ni = 0; ni < 8; ni++) {
            int n    = np * 128 + ni * 16 + c;
            int g    = n >> 8, rem = n & 255;
            int half = rem >> 7, colu = rem & 127;
            int np2  = half * 512 + colu * 4 + g;
            float bv = bias[n];
#pragma unroll
            for (int r = 0; r < 4; r++) {
                int row = i0 + wave * 16 + q * 4 + r;
                Zx[(size_t)row * N4H + np2] = (f16)(acc[ni][r] + bv);
            }
        }
    }
}

// ---------------------------------------------------------------------------
// K3: persistent LSTM, split-K pipelined pair exchange.
// 32 WGs x 512 thr; pair = wgid>>1 owns rows [16*pair,+16); half = wgid&1
// owns units [128*half,+128) x 4 gates. Wh slice pinned in AGPRs (opaque
// "=a" asm) and consumed DIRECTLY as MFMA B operand (no accvgpr_read).
// Per step: [poll+merge partner h_t] -> barrier -> partner-half K MFMA ->
// gates -> publish tagged h (L3) -> issue polls -> Zx consume -> outs ->
// barrier -> own-half K MFMA for t+1 (covers the exchange RTT).
//
// ROUND-4 CHANGE (only one): the two in-loop __syncthreads are replaced by
// LGKM_BARRIER (lgkmcnt(0) + raw s_barrier). __syncthreads' implicit
// vmcnt(0) drained the just-issued z-prefetch (~800cy exposed at barrier 1)
// and the in-flight partner polls + publish acks (~500cy at barrier 2) every
// step; neither drain is needed — the compiler inserts precise waits for its
// own loads before their uses (polls before the tag check [vmcnt(6): z and
// prev-iter outs stay in flight], z0/z1 before the Zx_s consume), and no
// cross-thread GLOBAL ordering in k3 depends on the barrier (Hex exchange is
// tag-validated). Everything else is byte-identical to the verified kernel.
// ---------------------------------------------------------------------------
__global__ __launch_bounds__(512, 2) void k3_lstm(
    const f16* __restrict__ Zx, const f16* __restrict__ WhT,
    const int* __restrict__ seqlen, f16* __restrict__ outs,
    f16* __restrict__ Hstate, float* __restrict__ Cstate,
    u32* __restrict__ Hex, int t0, int Tc, int first, int last) {
    __shared__ __align__(16) f16 Zx_s[2][16][520];  // [parity][row][512 cols]
    __shared__ __align__(16) f16 h_s[2][16][264];   // [parity][row][k]

    int tau  = threadIdx.x;
    int w    = tau >> 6, lane = tau & 63;
    int q = lane >> 4, c = lane & 15;
    int wgid = blockIdx.x;
    int pair = wgid >> 1, half = wgid & 1;
    int b0 = pair * 16;
    int u0 = half * 128, pu0 = (half ^ 1) * 128;
    int u  = u0 + w * 16 + c;   // this lane's hidden unit
    int col = w * 16 + c;       // unit index inside our 128-chunk

    u32* hexw_my = Hex + (size_t)wgid * 2 * 2048;        // [parity][16][128]
    u32* hexw_pr = Hex + (size_t)(wgid ^ 1) * 2 * 2048;

    // ---- Wh fragments pinned in AGPRs; slot s<4 = own-half K, s>=4 partner ----
    f32x4 wha[4][8];
#pragma unroll
    for (int g = 0; g < 4; g++)
#pragma unroll
        for (int s = 0; s < 8; s++) {
            int kc = (s < 4) ? (half * 4 + s) : ((half ^ 1) * 4 + (s - 4));
            f16x8 f = *(const f16x8*)(WhT +
                (size_t)(g * 256 + u0 + w * 16 + c) * 256 + kc * 32 + q * 8);
            f32x4 t = __builtin_bit_cast(f32x4, f);
            asm volatile("" : "=a"(wha[g][s]) : "0"(t));
        }

    // k-element offsets within an h_s row for the two K-halves
    int kOwn = half * 128 + q * 8;          // + kk*32
    int kPar = (half ^ 1) * 128 + q * 8;

    // ---- init h_s / cst / hprev ----
    int p0 = t0 & 1;
    if (first) {
        for (int idx = tau; idx < 2 * 16 * 264; idx += 512)
            ((f16*)h_s)[idx] = (f16)0.f;
    } else {
        for (int idx = tau; idx < 16 * 256; idx += 512) {
            int r = idx >> 8, k = idx & 255;
            h_s[p0][r][k] = Hstate[(b0 + r) * H_ + k];
        }
    }

    float cst[4];
    f16   hprev[4];
    int   sl[4];
#pragma unroll
    for (int r = 0; r < 4; r++) {
        int row = q * 4 + r;
        cst[r]   = first ? 0.f : Cstate[(b0 + row) * H_ + u];
        hprev[r] = first ? (f16)0.f : Hstate[(b0 + row) * H_ + u];
        sl[r]    = seqlen[b0 + row];
    }

    // Zx staging geometry: thread stages 32 B of row (tau>>5), cols (tau&31)*16
    int r_st = tau >> 5;
    int cc   = (tau & 31) * 16;
    const f16* zxrow = Zx + ((size_t)(b0 + r_st) * Tc) * N4H + half * 512 + cc;

    // prologue: fill Zx_s for step 0
    {
        const f16x8* src = (const f16x8*)zxrow;
        f16x8* dst = (f16x8*)&Zx_s[p0][r_st][cc];
        dst[0] = src[0];
        dst[1] = src[1];
    }
    // partner-merge geometry: thread handles 4 words: row tau>>5, cols (tau&31)*4
    int rr = tau >> 5;
    int uu = (tau & 31) * 4;

    __syncthreads();  // prologue: full drain once is fine

    // prologue: own-half partial MFMA from h_s[p0]
    f32x4 accO[4];
#pragma unroll
    for (int g = 0; g < 4; g++) accO[g] = (f32x4){0.f, 0.f, 0.f, 0.f};
#pragma unroll
    for (int kk = 0; kk < 4; kk++) {
        f16x8 afrag = *(const f16x8*)&h_s[p0][c][kOwn + kk * 32];
#pragma unroll
        for (int g = 0; g < 4; g++) MFMA_A(accO[g], afrag, wha[g][kk]);
    }

    u64 vp0 = 0, vp1 = 0;  // in-flight partner poll payload

    for (int tt = 0; tt < Tc; tt++) {
        int t   = t0 + tt;
        int cur = t & 1, nxt = cur ^ 1;

        // Zx prefetch for t+1 (max latency cover: consumed end of iteration)
        int tn = (tt + 1 < Tc) ? tt + 1 : tt;
        const f16x8* psrc = (const f16x8*)(zxrow + (size_t)tn * N4H);
        f16x8 z0 = psrc[0];
        f16x8 z1 = psrc[1];

        // poll + merge partner half of h_t (skip at chunk start: h_s complete)
        if (tt > 0) {
            u32 tagp = (u32)(t & 0xffff);
            const u64* pp = (const u64*)&hexw_pr[cur * 2048 + rr * 128 + uu];
            while (((u32)(vp0 >> 16) & 0xffffu) != tagp ||
                   ((u32)(vp0 >> 48)) != tagp ||
                   ((u32)(vp1 >> 16) & 0xffffu) != tagp ||
                   ((u32)(vp1 >> 48)) != tagp) {
                vp0 = __hip_atomic_load(pp + 0, __ATOMIC_RELAXED,
                                        __HIP_MEMORY_SCOPE_AGENT);
                vp1 = __hip_atomic_load(pp + 1, __ATOMIC_RELAXED,
                                        __HIP_MEMORY_SCOPE_AGENT);
            }
            u64 hw = (u64)(vp0 & 0xffff) | (((vp0 >> 32) & 0xffff) << 16) |
                     ((vp1 & 0xffff) << 32) | (((vp1 >> 32) & 0xffff) << 48);
            *(u64*)&h_s[cur][rr][pu0 + uu] = hw;
        }
        LGKM_BARRIER();  // partner half visible; h_s[cur] complete

        // partner-half K MFMA (slots 4-7) -> full pre-activations in accO
#pragma unroll
        for (int kk = 0; kk < 4; kk++) {
            f16x8 afrag = *(const f16x8*)&h_s[cur][c][kPar + kk * 32];
#pragma unroll
            for (int g = 0; g < 4; g++) MFMA_A(accO[g], afrag, wha[g][4 + kk]);
        }

        // gates (C layout: col=c, row=q*4+r); publish own h with tag t+1
        u32 tag = (u32)((t + 1) & 0xffff);
        f16 ovals[4];
#pragma unroll
        for (int r = 0; r < 4; r++) {
            int row = q * 4 + r;
            f16x4 zv = *(const f16x4*)&Zx_s[cur][row][col * 4];
            float zi = accO[0][r] + (float)zv[0];
            float zj = accO[1][r] + (float)zv[1];
            float zf = accO[2][r] + (float)zv[2];
            float zo = accO[3][r] + (float)zv[3];
            float ig = sigmoid_f(zi);
            float jg = tanh_f(zj);
            float fg = sigmoid_f(zf + 1.f);
            float og = sigmoid_f(zo);
            float cn = cst[r] * fg + ig * jg;
            float hn = tanh_f(cn) * og;
            bool  m  = (t < sl[r]);
            cst[r]   = m ? cn : cst[r];
            f16 hkeep = m ? (f16)hn : hprev[r];
            hprev[r]  = hkeep;
            h_s[nxt][row][u] = hkeep;
            u32 word = (tag << 16) |
                       (u32)(unsigned short)__builtin_bit_cast(short, hkeep);
            __hip_atomic_store(&hexw_my[nxt * 2048 + row * 128 + col], word,
                               __ATOMIC_RELAXED, __HIP_MEMORY_SCOPE_AGENT);
            ovals[r] = m ? (f16)hn : (f16)0.f;
        }

        // issue partner polls for h_{t+1} BEFORE outs stores (vmcnt in-order:
        // waiting on these loads later won't drain the HBM stores)
        {
            const u64* pp2 = (const u64*)&hexw_pr[nxt * 2048 + rr * 128 + uu];
            vp0 = __hip_atomic_load(pp2 + 0, __ATOMIC_RELAXED,
                                    __HIP_MEMORY_SCOPE_AGENT);
            vp1 = __hip_atomic_load(pp2 + 1, __ATOMIC_RELAXED,
                                    __HIP_MEMORY_SCOPE_AGENT);
        }

        // consume Zx prefetch into other parity
        {
            f16x8* dst = (f16x8*)&Zx_s[nxt][r_st][cc];
            dst[0] = z0;
            dst[1] = z1;
        }

        // outs stores (after poll issue)
#pragma unroll
        for (int r = 0; r < 4; r++)
            outs[((size_t)(b0 + q * 4 + r) * T_ + t) * H_ + u] = ovals[r];

        LGKM_BARRIER();  // own half of h_s[nxt] + Zx_s[nxt] ready

        // own-half K MFMA for step t+1 (slots 0-3) — covers exchange RTT
#pragma unroll
        for (int g = 0; g < 4; g++) accO[g] = (f32x4){0.f, 0.f, 0.f, 0.f};
#pragma unroll
        for (int kk = 0; kk < 4; kk++) {
            f16x8 afrag = *(const f16x8*)&h_s[nxt][c][kOwn + kk * 32];
#pragma unroll
            for (int g = 0; g < 4; g++) MFMA_A(accO[g], afrag, wha[g][kk]);
        }
    }

    if (!last) {
        int parity = (t0 + Tc) & 1;
        for (int idx = tau; idx < 16 * 128; idx += 512) {
            int r = idx >> 7, k = u0 + (idx & 127);
            Hstate[(b0 + r) * H_ + k] = h_s[parity][r][k];
        }
#pragma unroll
        for (int r = 0; r < 4; r++)
            Cstate[(b0 + q * 4 + r) * H_ + u] = cst[r];
    }
}

// ---------------------------------------------------------------------------
// K4: attention + head. One WG (256 thr) per batch row.
// ---------------------------------------------------------------------------
__global__ __launch_bounds__(256) void k4_attn(
    const f16* __restrict__ outs, const f16* __restrict__ WomT,
    const float* __restrict__ b_omega, const float* __restrict__ u_omega,
    const float* __restrict__ w, const float* __restrict__ bfin,
    float* __restrict__ out) {
    __shared__ __align__(16) f16 A_s[64][264];
    __shared__ __align__(16) f16 val_s[64][132];
    __shared__ float u_s[128];
    __shared__ float vu_s[512];
    __shared__ float red0[256], red1[256];

    int b = blockIdx.x, tau = threadIdx.x;
    int wave = tau >> 6, lane = tau & 63;
    int q = lane >> 4, c = lane & 15;

    if (tau < 128) u_s[tau] = u_omega[tau];
    float bom[8];
#pragma unroll
    for (int ni = 0; ni < 8; ni++) bom[ni] = b_omega[ni * 16 + c];

    for (int ch = 0; ch < 8; ch++) {
        int t0c = ch * 64;
        __syncthreads();  // protects A_s/val_s reuse (+ covers u_s init)
        {   // stage 64 rows of outs
            int r = tau >> 2, seg = tau & 3;
            const f16x8* src =
                (const f16x8*)(outs + ((size_t)b * T_ + t0c + r) * H_ + seg * 64);
            f16x8* dst = (f16x8*)&A_s[r][seg * 64];
#pragma unroll
            for (int j = 0; j < 8; j++) dst[j] = src[j];
        }
        __syncthreads();

        f32x4 acc[8];
#pragma unroll
        for (int ni = 0; ni < 8; ni++) acc[ni] = (f32x4){0.f, 0.f, 0.f, 0.f};
#pragma unroll
        for (int kc = 0; kc < 8; kc++) {
            f16x8 afrag = *(const f16x8*)&A_s[wave * 16 + c][kc * 32 + q * 8];
#pragma unroll
            for (int ni = 0; ni < 8; ni++) {
                f16x8 bfrag = *(const f16x8*)(WomT +
                    (size_t)(ni * 16 + c) * 256 + kc * 32 + q * 8);
                acc[ni] = __builtin_amdgcn_mfma_f32_16x16x32_f16(
                    afrag, bfrag, acc[ni], 0, 0, 0);
            }
        }
#pragma unroll
        for (int ni = 0; ni < 8; ni++) {
#pragma unroll
            for (int r = 0; r < 4; r++) {
                val_s[wave * 16 + q * 4 + r][ni * 16 + c] =
                    (f16)tanh_f(acc[ni][r] + bom[ni]);
            }
        }
        __syncthreads();
        if (tau < 64) {
            float s = 0.f;
#pragma unroll 8
            for (int a = 0; a < 128; a++) s += (float)val_s[tau][a] * u_s[a];
            vu_s[t0c + tau] = s;
        }
    }
    __syncthreads();

    // softmax over T=512
    red0[tau] = fmaxf(vu_s[tau], vu_s[tau + 256]);
    __syncthreads();
    for (int s = 128; s > 0; s >>= 1) {
        if (tau < s) red0[tau] = fmaxf(red0[tau], red0[tau + s]);
        __syncthreads();
    }
    float mx = red0[0];
    __syncthreads();
    float e0 = __expf(vu_s[tau] - mx), e1 = __expf(vu_s[tau + 256] - mx);
    red0[tau] = e0 + e1;
    __syncthreads();
    for (int s = 128; s > 0; s >>= 1) {
        if (tau < s) red0[tau] += red0[tau + s];
        __syncthreads();
    }
    float inv = 1.f / red0[0];
    __syncthreads();
    vu_s[tau]       = e0 * inv;
    vu_s[tau + 256] = e1 * inv;
    __syncthreads();

    // last[h] = sum_t alpha[t] * outs[b][t][h]   (tau = h)
    float lastv = 0.f;
#pragma unroll 4
    for (int t = 0; t < T_; t++)
        lastv += vu_s[t] * (float)outs[((size_t)b * T_ + t) * H_ + tau];

    // logits + 2-class softmax
    red0[tau] = lastv * w[tau * 2 + 0];
    red1[tau] = lastv * w[tau * 2 + 1];
    __syncthreads();
    for (int s = 128; s > 0; s >>= 1) {
        if (tau < s) {
            red0[tau] += red0[tau + s];
            red1[tau] += red1[tau + s];
        }
        __syncthreads();
    }
    if (tau == 0) {
        float l0 = red0[0] + bfin[0], l1 = red1[0] + bfin[1];
        float mm = fmaxf(l0, l1);
        float a0 = __expf(l0 - mm), a1 = __expf(l1 - mm);
        float den = a0 + a1;
        out[b * 2 + 0] = a0 / den;
        out[b * 2 + 1] = a1 / den;
    }
}

// ---------------------------------------------------------------------------
extern "C" void kernel_launch(void* const* d_in, const int* in_sizes, int n_in,
                              void* d_out, int out_size, void* d_ws,
                              size_t ws_size, hipStream_t stream) {
    const int*   x           = (const int*)d_in[0];
    const float* embed       = (const float*)d_in[1];
    const float* lstm_kernel = (const float*)d_in[2];
    const float* lstm_bias   = (const float*)d_in[3];
    const float* w_omega     = (const float*)d_in[4];
    const float* b_omega     = (const float*)d_in[5];
    const float* u_omega     = (const float*)d_in[6];
    const float* w           = (const float*)d_in[7];
    const float* bfin        = (const float*)d_in[8];
    float*       out         = (float*)d_out;

    char* ws = (char*)d_ws;
    f16*   WxT    = (f16*)(ws + 0);              //  524288 B
    f16*   WhT    = (f16*)(ws + 524288);         //  524288 B
    f16*   WomT   = (f16*)(ws + 1048576);        //   65536 B
    int*   seqlen = (int*)(ws + 1114112);        //    1024 B
    f16*   Hstate = (f16*)(ws + 1115136);        //  131072 B
    float* Cstate = (float*)(ws + 1246208);      //  262144 B
    u32*   Hex    = (u32*)(ws + 1508352);        //  524288 B (32 wg x 2 x 8KB)
    f16*   outs   = (f16*)(ws + 2032640);        // 67108864 B
    f16*   Zx     = (f16*)(ws + 2032640 + 67108864);

    const size_t fixed = 2032640ull + 67108864ull;
    int nch = 1;
    while (nch < 16 && fixed + 268435456ull / (size_t)nch > ws_size) nch <<= 1;
    int Tc = T_ / nch;

    k0_convert<<<1152, 256, 0, stream>>>(lstm_kernel, w_omega, WxT, WhT, WomT);
    k1_seqlen<<<256, 256, 0, stream>>>(x, seqlen);
    for (int chk = 0; chk < nch; chk++) {
        int t0 = chk * Tc;
        k2_zx<<<(B_ * Tc) / 64, 256, 0, stream>>>(x, embed, WxT, lstm_bias, Zx,
                                                  t0, Tc);
        k3_lstm<<<32, 512, 0, stream>>>(Zx, WhT, seqlen, outs, Hstate, Cstate,
                                        Hex, t0, Tc, chk == 0 ? 1 : 0,
                                        chk == nch - 1 ? 1 : 0);
    }
    k4_attn<<<256, 256, 0, stream>>>(outs, WomT, b_omega, u_omega, w, bfin, out);
}

// Round 5
// 1447.051 us; speedup vs baseline: 1.2411x; 1.0951x over previous
//
#include <hip/hip_runtime.h>
#include <hip/hip_bf16.h>
#include <cstdint>
#include <cstddef>

typedef _Float16 f16;
typedef _Float16 f16x8 __attribute__((ext_vector_type(8)));
typedef _Float16 f16x4 __attribute__((ext_vector_type(4)));
typedef float f32x4 __attribute__((ext_vector_type(4)));
typedef unsigned long long u64;
typedef unsigned int u32;

#define B_   256
#define T_   512
#define V_   50000
#define D_   256
#define H_   256
#define A_   128
#define N4H  1024

__device__ __forceinline__ float sigmoid_f(float x) {
    return __builtin_amdgcn_rcpf(1.f + __expf(-x));
}
__device__ __forceinline__ float tanh_f(float x) {
    float e = __expf(-2.f * fabsf(x));
    float t = 1.f - 2.f * e * __builtin_amdgcn_rcpf(1.f + e);
    return copysignf(t, x);
}

// asm MFMA with B operand taken straight from AGPRs (no accvgpr_read moves)
#define MFMA_A(accv, afragv, bfraga)                                         \
    asm volatile("v_mfma_f32_16x16x32_f16 %0, %1, %2, %0"                    \
                 : "+v"(accv) : "v"(afragv), "a"(bfraga))

// LDS-drain-only barrier: keeps global loads/stores (polls!) in flight
// across the barrier; only LDS ordering is enforced. Verified round 4.
#define LGKM_BARRIER()                                                       \
    do {                                                                     \
        asm volatile("s_waitcnt lgkmcnt(0)" ::: "memory");                   \
        __builtin_amdgcn_sched_barrier(0);                                   \
        __builtin_amdgcn_s_barrier();                                        \
        __builtin_amdgcn_sched_barrier(0);                                   \
    } while (0)

// ---------------------------------------------------------------------------
// K0: weight transpose + fp32->fp16 cast.
// ---------------------------------------------------------------------------
__global__ __launch_bounds__(256) void k0_convert(
    const float* __restrict__ lstm_kernel, const float* __restrict__ w_omega,
    f16* __restrict__ WxT, f16* __restrict__ WhT, f16* __restrict__ WomT) {
    int blk = blockIdx.x;
    int tau = threadIdx.x;  // 0..255 (= k / h index)
    if (blk < N4H) {
        int n = blk;
        WxT[n * 256 + tau] = (f16)lstm_kernel[(size_t)tau * N4H + n];
        WhT[n * 256 + tau] = (f16)lstm_kernel[(size_t)(256 + tau) * N4H + n];
    } else {
        int a = blk - N4H;  // 0..127
        WomT[a * 256 + tau] = (f16)w_omega[(size_t)tau * A_ + a];
    }
}

// ---------------------------------------------------------------------------
// K1: seq_len[b] = sum_t (x[b,t] != 0)
// ---------------------------------------------------------------------------
__global__ __launch_bounds__(256) void k1_seqlen(
    const int* __restrict__ x, int* __restrict__ seqlen) {
    __shared__ int red[256];
    int b = blockIdx.x, tau = threadIdx.x;
    int cnt = (x[b * T_ + tau] != 0) + (x[b * T_ + tau + 256] != 0);
    red[tau] = cnt;
    __syncthreads();
    for (int s = 128; s > 0; s >>= 1) {
        if (tau < s) red[tau] += red[tau + s];
        __syncthreads();
    }
    if (tau == 0) seqlen[b] = red[0];
}

// ---------------------------------------------------------------------------
// K2: Zx = embed[x] @ Wx + bias, fp16 (standalone, 256 thr, chunk 0 only).
// Column layout is half-split AND gate-interleaved:
// n = g*256 + half*128 + colu -> n'' = half*512 + colu*4 + g
// so k3 reads {i,j,f,o} for one unit as ONE ds_read_b64.
// ---------------------------------------------------------------------------
__global__ __launch_bounds__(256) void k2_zx(
    const int* __restrict__ x, const float* __restrict__ embed,
    const f16* __restrict__ WxT, const float* __restrict__ bias,
    f16* __restrict__ Zx, int t0, int Tc) {
    __shared__ __align__(16) f16 A_s[64][264];   // [m][k], pad 8
    __shared__ __align__(16) f16 B_s[128][72];   // [n][k-slice], pad 8
    __shared__ int tok_s[64];

    int tau  = threadIdx.x;
    int bm   = blockIdx.x;
    int i0   = bm * 64;
    int wave = tau >> 6, lane = tau & 63;
    int q = lane >> 4, c = lane & 15;

    if (tau < 64) {
        int i  = i0 + tau;
        int bb = i / Tc, tr = i - bb * Tc;
        tok_s[tau] = x[bb * T_ + t0 + tr];
    }
    __syncthreads();

    // gather A: 64 rows x 256 f32 -> fp16 LDS. 4 threads/row, 16 float4 each.
    {
        int r = tau >> 2, quarter = tau & 3;
        const float4* src =
            (const float4*)(embed + (size_t)tok_s[r] * D_ + quarter * 64);
        f16* dst = &A_s[r][quarter * 64];
#pragma unroll
        for (int j = 0; j < 16; j++) {
            float4 v = src[j];
            dst[j * 4 + 0] = (f16)v.x;
            dst[j * 4 + 1] = (f16)v.y;
            dst[j * 4 + 2] = (f16)v.z;
            dst[j * 4 + 3] = (f16)v.w;
        }
    }

    for (int np = 0; np < 8; np++) {
        f32x4 acc[8];
#pragma unroll
        for (int ni = 0; ni < 8; ni++) acc[ni] = (f32x4){0.f, 0.f, 0.f, 0.f};

        for (int kt = 0; kt < 4; kt++) {
            __syncthreads();  // previous B_s consumers done
            {
                int n = tau >> 1, half = tau & 1;
                const f16x8* src = (const f16x8*)(WxT +
                    (size_t)(np * 128 + n) * 256 + kt * 64 + half * 32);
                f16x8* dst = (f16x8*)&B_s[n][half * 32];
#pragma unroll
                for (int j = 0; j < 4; j++) dst[j] = src[j];
            }
            __syncthreads();
#pragma unroll
            for (int s = 0; s < 2; s++) {
                f16x8 afrag =
                    *(const f16x8*)&A_s[wave * 16 + c][kt * 64 + s * 32 + q * 8];
#pragma unroll
                for (int ni = 0; ni < 8; ni++) {
                    f16x8 bfrag = *(const f16x8*)&B_s[ni * 16 + c][s * 32 + q * 8];
                    acc[ni] = __builtin_amdgcn_mfma_f32_16x16x32_f16(
                        afrag, bfrag, acc[ni], 0, 0, 0);
                }
            }
        }
        // epilogue (half-split + gate-interleaved column write)
#pragma unroll
        for (int ni = 0; ni < 8; ni++) {
            int n    = np * 128 + ni * 16 + c;
            int g    = n >> 8, rem = n & 255;
            int half = rem >> 7, colu = rem & 127;
            int np2  = half * 512 + colu * 4 + g;
            float bv = bias[n];
#pragma unroll
            for (int r = 0; r < 4; r++) {
                int row = i0 + wave * 16 + q * 4 + r;
                Zx[(size_t)row * N4H + np2] = (f16)(acc[ni][r] + bv);
            }
        }
    }
}

// ---------------------------------------------------------------------------
// Zx producer, 512-thread variant of k2 (128 rows/block). Runs as the extra
// blocks (blockIdx >= 32) of the fused k3 launch, computing the NEXT chunk's
// Zx into the other double buffer while the 32 LSTM blocks run the current
// chunk. No synchronization with the LSTM blocks is needed: disjoint buffers,
// and chunk k+1's k3 launch begins only after this launch fully completes.
// ---------------------------------------------------------------------------
__device__ __forceinline__ void zx_producer(
    const int* __restrict__ x, const float* __restrict__ embed,
    const f16* __restrict__ WxT, const float* __restrict__ bias,
    f16* __restrict__ Zx, int pb, int t0, int Tc) {
    __shared__ __align__(16) f16 Ap_s[128][264];
    __shared__ __align__(16) f16 Bp_s[128][72];
    __shared__ int tokp_s[128];

    int tau  = threadIdx.x;           // 0..511
    int i0   = pb * 128;
    int wave = tau >> 6, lane = tau & 63;
    int q = lane >> 4, c = lane & 15;

    if (tau < 128) {
        int i  = i0 + tau;
        int bb = i / Tc, tr = i - bb * Tc;
        tokp_s[tau] = x[bb * T_ + t0 + tr];
    }
    __syncthreads();

    // gather A: 128 rows x 256 f32 -> fp16 LDS. 4 threads/row.
    {
        int r = tau >> 2, quarter = tau & 3;
        const float4* src =
            (const float4*)(embed + (size_t)tokp_s[r] * D_ + quarter * 64);
        f16* dst = &Ap_s[r][quarter * 64];
#pragma unroll
        for (int j = 0; j < 16; j++) {
            float4 v = src[j];
            dst[j * 4 + 0] = (f16)v.x;
            dst[j * 4 + 1] = (f16)v.y;
            dst[j * 4 + 2] = (f16)v.z;
            dst[j * 4 + 3] = (f16)v.w;
        }
    }

    for (int np = 0; np < 8; np++) {
        f32x4 acc[8];
#pragma unroll
        for (int ni = 0; ni < 8; ni++) acc[ni] = (f32x4){0.f, 0.f, 0.f, 0.f};

        for (int kt = 0; kt < 4; kt++) {
            __syncthreads();  // previous B_s consumers done (covers A_s fill)
            {
                int n = tau >> 2, qt = tau & 3;   // 128 n x 4 x 16 elems
                const f16x8* src = (const f16x8*)(WxT +
                    (size_t)(np * 128 + n) * 256 + kt * 64 + qt * 16);
                f16x8* dst = (f16x8*)&Bp_s[n][qt * 16];
                dst[0] = src[0];
                dst[1] = src[1];
            }
            __syncthreads();
#pragma unroll
            for (int s = 0; s < 2; s++) {
                f16x8 afrag =
                    *(const f16x8*)&Ap_s[wave * 16 + c][kt * 64 + s * 32 + q * 8];
#pragma unroll
                for (int ni = 0; ni < 8; ni++) {
                    f16x8 bfrag = *(const f16x8*)&Bp_s[ni * 16 + c][s * 32 + q * 8];
                    acc[ni] = __builtin_amdgcn_mfma_f32_16x16x32_f16(
                        afrag, bfrag, acc[ni], 0, 0, 0);
                }
            }
        }
#pragma unroll
        for (int ni = 0; ni < 8; ni++) {
            int n     = np * 128 + ni * 16 + c;
            int g     = n >> 8, rem = n & 255;
            int halfn = rem >> 7, colu = rem & 127;
            int np2   = halfn * 512 + colu * 4 + g;
            float bv  = bias[n];
#pragma unroll
            for (int r = 0; r < 4; r++) {
                int row = i0 + wave * 16 + q * 4 + r;
                Zx[(size_t)row * N4H + np2] = (f16)(acc[ni][r] + bv);
            }
        }
    }
}

// ---------------------------------------------------------------------------
// K3: persistent LSTM, split-K pipelined pair exchange (verified structure),
// fused with the next-chunk Zx producer (blocks >= 32).
//
// LSTM blocks are blockIdx 0..31 -> dispatched first -> resident first; the
// producer blocks have no inter-block sync, so no scheduling order can
// deadlock the pair spin (worst case is delay).
//
// ROUND-5 LSTM change (one): the two prefetch polls are issued AFTER the
// Zx_s consume + outs stores (last vmem ops before the barrier) instead of
// before them. They sample L3 ~200cy later — past the partner's symmetric
// publish-to-L3 latency — raising the first-poll hit rate; each converted
// miss saves a full ~600cy respin. LGKM_BARRIER (round 4) keeps them in
// flight across the barrier; next iteration's check still gets a counted
// vmcnt(2) wait (only the z-prefetch loads are younger).
// ---------------------------------------------------------------------------
__global__ __launch_bounds__(512, 2) void k3_lstm(
    const f16* __restrict__ Zx, const f16* __restrict__ WhT,
    const int* __restrict__ seqlen, f16* __restrict__ outs,
    f16* __restrict__ Hstate, float* __restrict__ Cstate,
    u32* __restrict__ Hex, int t0, int Tc, int first, int last,
    const int* __restrict__ x, const float* __restrict__ embed,
    const f16* __restrict__ WxT, const float* __restrict__ bias,
    f16* __restrict__ ZxNext, int t0n) {
    if (blockIdx.x >= 32) {  // next-chunk Zx producer
        zx_producer(x, embed, WxT, bias, ZxNext, blockIdx.x - 32, t0n, Tc);
        return;
    }

    __shared__ __align__(16) f16 Zx_s[2][16][520];  // [parity][row][512 cols]
    __shared__ __align__(16) f16 h_s[2][16][264];   // [parity][row][k]

    int tau  = threadIdx.x;
    int w    = tau >> 6, lane = tau & 63;
    int q = lane >> 4, c = lane & 15;
    int wgid = blockIdx.x;
    int pair = wgid >> 1, half = wgid & 1;
    int b0 = pair * 16;
    int u0 = half * 128, pu0 = (half ^ 1) * 128;
    int u  = u0 + w * 16 + c;   // this lane's hidden unit
    int col = w * 16 + c;       // unit index inside our 128-chunk

    u32* hexw_my = Hex + (size_t)wgid * 2 * 2048;        // [parity][16][128]
    u32* hexw_pr = Hex + (size_t)(wgid ^ 1) * 2 * 2048;

    // ---- Wh fragments pinned in AGPRs; slot s<4 = own-half K, s>=4 partner ----
    f32x4 wha[4][8];
#pragma unroll
    for (int g = 0; g < 4; g++)
#pragma unroll
        for (int s = 0; s < 8; s++) {
            int kc = (s < 4) ? (half * 4 + s) : ((half ^ 1) * 4 + (s - 4));
            f16x8 f = *(const f16x8*)(WhT +
                (size_t)(g * 256 + u0 + w * 16 + c) * 256 + kc * 32 + q * 8);
            f32x4 t = __builtin_bit_cast(f32x4, f);
            asm volatile("" : "=a"(wha[g][s]) : "0"(t));
        }

    // k-element offsets within an h_s row for the two K-halves
    int kOwn = half * 128 + q * 8;          // + kk*32
    int kPar = (half ^ 1) * 128 + q * 8;

    // ---- init h_s / cst / hprev ----
    int p0 = t0 & 1;
    if (first) {
        for (int idx = tau; idx < 2 * 16 * 264; idx += 512)
            ((f16*)h_s)[idx] = (f16)0.f;
    } else {
        for (int idx = tau; idx < 16 * 256; idx += 512) {
            int r = idx >> 8, k = idx & 255;
            h_s[p0][r][k] = Hstate[(b0 + r) * H_ + k];
        }
    }

    float cst[4];
    f16   hprev[4];
    int   sl[4];
#pragma unroll
    for (int r = 0; r < 4; r++) {
        int row = q * 4 + r;
        cst[r]   = first ? 0.f : Cstate[(b0 + row) * H_ + u];
        hprev[r] = first ? (f16)0.f : Hstate[(b0 + row) * H_ + u];
        sl[r]    = seqlen[b0 + row];
    }

    // Zx staging geometry: thread stages 32 B of row (tau>>5), cols (tau&31)*16
    int r_st = tau >> 5;
    int cc   = (tau & 31) * 16;
    const f16* zxrow = Zx + ((size_t)(b0 + r_st) * Tc) * N4H + half * 512 + cc;

    // prologue: fill Zx_s for step 0
    {
        const f16x8* src = (const f16x8*)zxrow;
        f16x8* dst = (f16x8*)&Zx_s[p0][r_st][cc];
        dst[0] = src[0];
        dst[1] = src[1];
    }
    // partner-merge geometry: thread handles 4 words: row tau>>5, cols (tau&31)*4
    int rr = tau >> 5;
    int uu = (tau & 31) * 4;

    __syncthreads();  // prologue: full drain once is fine

    // prologue: own-half partial MFMA from h_s[p0]
    f32x4 accO[4];
#pragma unroll
    for (int g = 0; g < 4; g++) accO[g] = (f32x4){0.f, 0.f, 0.f, 0.f};
#pragma unroll
    for (int kk = 0; kk < 4; kk++) {
        f16x8 afrag = *(const f16x8*)&h_s[p0][c][kOwn + kk * 32];
#pragma unroll
        for (int g = 0; g < 4; g++) MFMA_A(accO[g], afrag, wha[g][kk]);
    }

    u64 vp0 = 0, vp1 = 0;  // in-flight partner poll payload

    for (int tt = 0; tt < Tc; tt++) {
        int t   = t0 + tt;
        int cur = t & 1, nxt = cur ^ 1;

        // Zx prefetch for t+1 (max latency cover: consumed end of iteration)
        int tn = (tt + 1 < Tc) ? tt + 1 : tt;
        const f16x8* psrc = (const f16x8*)(zxrow + (size_t)tn * N4H);
        f16x8 z0 = psrc[0];
        f16x8 z1 = psrc[1];

        // poll + merge partner half of h_t (skip at chunk start: h_s complete)
        if (tt > 0) {
            u32 tagp = (u32)(t & 0xffff);
            const u64* pp = (const u64*)&hexw_pr[cur * 2048 + rr * 128 + uu];
            while (((u32)(vp0 >> 16) & 0xffffu) != tagp ||
                   ((u32)(vp0 >> 48)) != tagp ||
                   ((u32)(vp1 >> 16) & 0xffffu) != tagp ||
                   ((u32)(vp1 >> 48)) != tagp) {
                vp0 = __hip_atomic_load(pp + 0, __ATOMIC_RELAXED,
                                        __HIP_MEMORY_SCOPE_AGENT);
                vp1 = __hip_atomic_load(pp + 1, __ATOMIC_RELAXED,
                                        __HIP_MEMORY_SCOPE_AGENT);
            }
            u64 hw = (u64)(vp0 & 0xffff) | (((vp0 >> 32) & 0xffff) << 16) |
                     ((vp1 & 0xffff) << 32) | (((vp1 >> 32) & 0xffff) << 48);
            *(u64*)&h_s[cur][rr][pu0 + uu] = hw;
        }
        LGKM_BARRIER();  // partner half visible; h_s[cur] complete

        // partner-half K MFMA (slots 4-7) -> full pre-activations in accO
#pragma unroll
        for (int kk = 0; kk < 4; kk++) {
            f16x8 afrag = *(const f16x8*)&h_s[cur][c][kPar + kk * 32];
#pragma unroll
            for (int g = 0; g < 4; g++) MFMA_A(accO[g], afrag, wha[g][4 + kk]);
        }

        // gates (C layout: col=c, row=q*4+r); publish own h with tag t+1
        u32 tag = (u32)((t + 1) & 0xffff);
        f16 ovals[4];
#pragma unroll
        for (int r = 0; r < 4; r++) {
            int row = q * 4 + r;
            f16x4 zv = *(const f16x4*)&Zx_s[cur][row][col * 4];
            float zi = accO[0][r] + (float)zv[0];
            float zj = accO[1][r] + (float)zv[1];
            float zf = accO[2][r] + (float)zv[2];
            float zo = accO[3][r] + (float)zv[3];
            float ig = sigmoid_f(zi);
            float jg = tanh_f(zj);
            float fg = sigmoid_f(zf + 1.f);
            float og = sigmoid_f(zo);
            float cn = cst[r] * fg + ig * jg;
            float hn = tanh_f(cn) * og;
            bool  m  = (t < sl[r]);
            cst[r]   = m ? cn : cst[r];
            f16 hkeep = m ? (f16)hn : hprev[r];
            hprev[r]  = hkeep;
            h_s[nxt][row][u] = hkeep;
            u32 word = (tag << 16) |
                       (u32)(unsigned short)__builtin_bit_cast(short, hkeep);
            __hip_atomic_store(&hexw_my[nxt * 2048 + row * 128 + col], word,
                               __ATOMIC_RELAXED, __HIP_MEMORY_SCOPE_AGENT);
            ovals[r] = m ? (f16)hn : (f16)0.f;
        }

        // consume Zx prefetch into other parity
        {
            f16x8* dst = (f16x8*)&Zx_s[nxt][r_st][cc];
            dst[0] = z0;
            dst[1] = z1;
        }

        // outs stores
#pragma unroll
        for (int r = 0; r < 4; r++)
            outs[((size_t)(b0 + q * 4 + r) * T_ + t) * H_ + u] = ovals[r];

        // issue partner polls for h_{t+1} LAST (round-5 move): sample L3
        // ~200cy later than the pre-outs placement -> first-poll hit more
        // likely. They stay in flight across LGKM_BARRIER; next iteration's
        // check uses a counted vmcnt(2) wait (z-prefetch younger), which
        // also implies the older outs-store acks have retired.
        {
            const u64* pp2 = (const u64*)&hexw_pr[nxt * 2048 + rr * 128 + uu];
            vp0 = __hip_atomic_load(pp2 + 0, __ATOMIC_RELAXED,
                                    __HIP_MEMORY_SCOPE_AGENT);
            vp1 = __hip_atomic_load(pp2 + 1, __ATOMIC_RELAXED,
                                    __HIP_MEMORY_SCOPE_AGENT);
        }

        LGKM_BARRIER();  // own half of h_s[nxt] + Zx_s[nxt] ready

        // own-half K MFMA for step t+1 (slots 0-3) — covers exchange RTT
#pragma unroll
        for (int g = 0; g < 4; g++) accO[g] = (f32x4){0.f, 0.f, 0.f, 0.f};
#pragma unroll
        for (int kk = 0; kk < 4; kk++) {
            f16x8 afrag = *(const f16x8*)&h_s[nxt][c][kOwn + kk * 32];
#pragma unroll
            for (int g = 0; g < 4; g++) MFMA_A(accO[g], afrag, wha[g][kk]);
        }
    }

    if (!last) {
        int parity = (t0 + Tc) & 1;
        for (int idx = tau; idx < 16 * 128; idx += 512) {
            int r = idx >> 7, k = u0 + (idx & 127);
            Hstate[(b0 + r) * H_ + k] = h_s[parity][r][k];
        }
#pragma unroll
        for (int r = 0; r < 4; r++)
            Cstate[(b0 + q * 4 + r) * H_ + u] = cst[r];
    }
}

// ---------------------------------------------------------------------------
// K4: attention + head. One WG (256 thr) per batch row.
// ---------------------------------------------------------------------------
__global__ __launch_bounds__(256) void k4_attn(
    const f16* __restrict__ outs, const f16* __restrict__ WomT,
    const float* __restrict__ b_omega, const float* __restrict__ u_omega,
    const float* __restrict__ w, const float* __restrict__ bfin,
    float* __restrict__ out) {
    __shared__ __align__(16) f16 A_s[64][264];
    __shared__ __align__(16) f16 val_s[64][132];
    __shared__ float u_s[128];
    __shared__ float vu_s[512];
    __shared__ float red0[256], red1[256];

    int b = blockIdx.x, tau = threadIdx.x;
    int wave = tau >> 6, lane = tau & 63;
    int q = lane >> 4, c = lane & 15;

    if (tau < 128) u_s[tau] = u_omega[tau];
    float bom[8];
#pragma unroll
    for (int ni = 0; ni < 8; ni++) bom[ni] = b_omega[ni * 16 + c];

    for (int ch = 0; ch < 8; ch++) {
        int t0c = ch * 64;
        __syncthreads();  // protects A_s/val_s reuse (+ covers u_s init)
        {   // stage 64 rows of outs
            int r = tau >> 2, seg = tau & 3;
            const f16x8* src =
                (const f16x8*)(outs + ((size_t)b * T_ + t0c + r) * H_ + seg * 64);
            f16x8* dst = (f16x8*)&A_s[r][seg * 64];
#pragma unroll
            for (int j = 0; j < 8; j++) dst[j] = src[j];
        }
        __syncthreads();

        f32x4 acc[8];
#pragma unroll
        for (int ni = 0; ni < 8; ni++) acc[ni] = (f32x4){0.f, 0.f, 0.f, 0.f};
#pragma unroll
        for (int kc = 0; kc < 8; kc++) {
            f16x8 afrag = *(const f16x8*)&A_s[wave * 16 + c][kc * 32 + q * 8];
#pragma unroll
            for (int ni = 0; ni < 8; ni++) {
                f16x8 bfrag = *(const f16x8*)(WomT +
                    (size_t)(ni * 16 + c) * 256 + kc * 32 + q * 8);
                acc[ni] = __builtin_amdgcn_mfma_f32_16x16x32_f16(
                    afrag, bfrag, acc[ni], 0, 0, 0);
            }
        }
#pragma unroll
        for (int ni = 0; ni < 8; ni++) {
#pragma unroll
            for (int r = 0; r < 4; r++) {
                val_s[wave * 16 + q * 4 + r][ni * 16 + c] =
                    (f16)tanh_f(acc[ni][r] + bom[ni]);
            }
        }
        __syncthreads();
        if (tau < 64) {
            float s = 0.f;
#pragma unroll 8
            for (int a = 0; a < 128; a++) s += (float)val_s[tau][a] * u_s[a];
            vu_s[t0c + tau] = s;
        }
    }
    __syncthreads();

    // softmax over T=512
    red0[tau] = fmaxf(vu_s[tau], vu_s[tau + 256]);
    __syncthreads();
    for (int s = 128; s > 0; s >>= 1) {
        if (tau < s) red0[tau] = fmaxf(red0[tau], red0[tau + s]);
        __syncthreads();
    }
    float mx = red0[0];
    __syncthreads();
    float e0 = __expf(vu_s[tau] - mx), e1 = __expf(vu_s[tau + 256] - mx);
    red0[tau] = e0 + e1;
    __syncthreads();
    for (int s = 128; s > 0; s >>= 1) {
        if (tau < s) red0[tau] += red0[tau + s];
        __syncthreads();
    }
    float inv = 1.f / red0[0];
    __syncthreads();
    vu_s[tau]       = e0 * inv;
    vu_s[tau + 256] = e1 * inv;
    __syncthreads();

    // last[h] = sum_t alpha[t] * outs[b][t][h]   (tau = h)
    float lastv = 0.f;
#pragma unroll 4
    for (int t = 0; t < T_; t++)
        lastv += vu_s[t] * (float)outs[((size_t)b * T_ + t) * H_ + tau];

    // logits + 2-class softmax
    red0[tau] = lastv * w[tau * 2 + 0];
    red1[tau] = lastv * w[tau * 2 + 1];
    __syncthreads();
    for (int s = 128; s > 0; s >>= 1) {
        if (tau < s) {
            red0[tau] += red0[tau + s];
            red1[tau] += red1[tau + s];
        }
        __syncthreads();
    }
    if (tau == 0) {
        float l0 = red0[0] + bfin[0], l1 = red1[0] + bfin[1];
        float mm = fmaxf(l0, l1);
        float a0 = __expf(l0 - mm), a1 = __expf(l1 - mm);
        float den = a0 + a1;
        out[b * 2 + 0] = a0 / den;
        out[b * 2 + 1] = a1 / den;
    }
}

// ---------------------------------------------------------------------------
extern "C" void kernel_launch(void* const* d_in, const int* in_sizes, int n_in,
                              void* d_out, int out_size, void* d_ws,
                              size_t ws_size, hipStream_t stream) {
    const int*   x           = (const int*)d_in[0];
    const float* embed       = (const float*)d_in[1];
    const float* lstm_kernel = (const float*)d_in[2];
    const float* lstm_bias   = (const float*)d_in[3];
    const float* w_omega     = (const float*)d_in[4];
    const float* b_omega     = (const float*)d_in[5];
    const float* u_omega     = (const float*)d_in[6];
    const float* w           = (const float*)d_in[7];
    const float* bfin        = (const float*)d_in[8];
    float*       out         = (float*)d_out;

    char* ws = (char*)d_ws;
    f16*   WxT    = (f16*)(ws + 0);              //  524288 B
    f16*   WhT    = (f16*)(ws + 524288);         //  524288 B
    f16*   WomT   = (f16*)(ws + 1048576);        //   65536 B
    int*   seqlen = (int*)(ws + 1114112);        //    1024 B
    f16*   Hstate = (f16*)(ws + 1115136);        //  131072 B
    float* Cstate = (float*)(ws + 1246208);      //  262144 B
    u32*   Hex    = (u32*)(ws + 1508352);        //  524288 B (32 wg x 2 x 8KB)
    f16*   outs   = (f16*)(ws + 2032640);        // 67108864 B

    // Zx double buffer for producer-fusion: need fixed + 2 chunks <= ws.
    const size_t fixed = 2032640ull + 67108864ull;
    int nch = 1;
    while (nch < 16 && fixed + 2ull * (268435456ull / (size_t)nch) > ws_size)
        nch <<= 1;
    int Tc = T_ / nch;
    size_t chunkB = 268435456ull / (size_t)nch;
    f16* ZxA = (f16*)(ws + fixed);
    f16* ZxB = (f16*)(ws + fixed + chunkB);  // unused when nch == 1

    k0_convert<<<1152, 256, 0, stream>>>(lstm_kernel, w_omega, WxT, WhT, WomT);
    k1_seqlen<<<256, 256, 0, stream>>>(x, seqlen);
    // chunk 0's Zx is the only one computed standalone
    k2_zx<<<(B_ * Tc) / 64, 256, 0, stream>>>(x, embed, WxT, lstm_bias, ZxA,
                                              0, Tc);
    for (int chk = 0; chk < nch; chk++) {
        int  t0  = chk * Tc;
        f16* zc  = (chk & 1) ? ZxB : ZxA;
        f16* zn  = (chk & 1) ? ZxA : ZxB;
        int  np  = (chk + 1 < nch) ? (B_ * Tc) / 128 : 0;  // producer blocks
        int  t0n = (chk + 1) * Tc;
        k3_lstm<<<32 + np, 512, 0, stream>>>(
            zc, WhT, seqlen, outs, Hstate, Cstate, Hex, t0, Tc,
            chk == 0 ? 1 : 0, chk == nch - 1 ? 1 : 0,
            x, embed, WxT, lstm_bias, zn, t0n);
    }
    k4_attn<<<256, 256, 0, stream>>>(outs, WomT, b_omega, u_omega, w, bfin, out);
}

// Round 6
// 1442.981 us; speedup vs baseline: 1.2446x; 1.0028x over previous
//
#include <hip/hip_runtime.h>
#include <hip/hip_bf16.h>
#include <cstdint>
#include <cstddef>

typedef _Float16 f16;
typedef _Float16 f16x8 __attribute__((ext_vector_type(8)));
typedef _Float16 f16x4 __attribute__((ext_vector_type(4)));
typedef float f32x4 __attribute__((ext_vector_type(4)));
typedef unsigned long long u64;
typedef unsigned int u32;

#define B_   256
#define T_   512
#define V_   50000
#define D_   256
#define H_   256
#define A_   128
#define N4H  1024

__device__ __forceinline__ float sigmoid_f(float x) {
    return __builtin_amdgcn_rcpf(1.f + __expf(-x));
}
__device__ __forceinline__ float tanh_f(float x) {
    float e = __expf(-2.f * fabsf(x));
    float t = 1.f - 2.f * e * __builtin_amdgcn_rcpf(1.f + e);
    return copysignf(t, x);
}

// asm MFMA with B operand taken straight from AGPRs (no accvgpr_read moves)
#define MFMA_A(accv, afragv, bfraga)                                         \
    asm volatile("v_mfma_f32_16x16x32_f16 %0, %1, %2, %0"                    \
                 : "+v"(accv) : "v"(afragv), "a"(bfraga))

// LDS-drain-only barrier: keeps global loads/stores (polls!) in flight
// across the barrier; only LDS ordering is enforced. Verified round 4.
#define LGKM_BARRIER()                                                       \
    do {                                                                     \
        asm volatile("s_waitcnt lgkmcnt(0)" ::: "memory");                   \
        __builtin_amdgcn_sched_barrier(0);                                   \
        __builtin_amdgcn_s_barrier();                                        \
        __builtin_amdgcn_sched_barrier(0);                                   \
    } while (0)

// ---------------------------------------------------------------------------
// K0: weight transpose + fp32->fp16 cast.
// ---------------------------------------------------------------------------
__global__ __launch_bounds__(256) void k0_convert(
    const float* __restrict__ lstm_kernel, const float* __restrict__ w_omega,
    f16* __restrict__ WxT, f16* __restrict__ WhT, f16* __restrict__ WomT) {
    int blk = blockIdx.x;
    int tau = threadIdx.x;  // 0..255 (= k / h index)
    if (blk < N4H) {
        int n = blk;
        WxT[n * 256 + tau] = (f16)lstm_kernel[(size_t)tau * N4H + n];
        WhT[n * 256 + tau] = (f16)lstm_kernel[(size_t)(256 + tau) * N4H + n];
    } else {
        int a = blk - N4H;  // 0..127
        WomT[a * 256 + tau] = (f16)w_omega[(size_t)tau * A_ + a];
    }
}

// ---------------------------------------------------------------------------
// K1: seq_len[b] = sum_t (x[b,t] != 0)
// ---------------------------------------------------------------------------
__global__ __launch_bounds__(256) void k1_seqlen(
    const int* __restrict__ x, int* __restrict__ seqlen) {
    __shared__ int red[256];
    int b = blockIdx.x, tau = threadIdx.x;
    int cnt = (x[b * T_ + tau] != 0) + (x[b * T_ + tau + 256] != 0);
    red[tau] = cnt;
    __syncthreads();
    for (int s = 128; s > 0; s >>= 1) {
        if (tau < s) red[tau] += red[tau + s];
        __syncthreads();
    }
    if (tau == 0) seqlen[b] = red[0];
}

// ---------------------------------------------------------------------------
// K2: Zx = embed[x] @ Wx + bias, fp16 (standalone, 256 thr, chunk 0 only).
// Column layout is half-split AND gate-interleaved:
// n = g*256 + half*128 + colu -> n'' = half*512 + colu*4 + g
// so k3 reads {i,j,f,o} for one unit as ONE ds_read_b64.
// ---------------------------------------------------------------------------
__global__ __launch_bounds__(256) void k2_zx(
    const int* __restrict__ x, const float* __restrict__ embed,
    const f16* __restrict__ WxT, const float* __restrict__ bias,
    f16* __restrict__ Zx, int t0, int Tc) {
    __shared__ __align__(16) f16 A_s[64][264];   // [m][k], pad 8
    __shared__ __align__(16) f16 B_s[128][72];   // [n][k-slice], pad 8
    __shared__ int tok_s[64];

    int tau  = threadIdx.x;
    int bm   = blockIdx.x;
    int i0   = bm * 64;
    int wave = tau >> 6, lane = tau & 63;
    int q = lane >> 4, c = lane & 15;

    if (tau < 64) {
        int i  = i0 + tau;
        int bb = i / Tc, tr = i - bb * Tc;
        tok_s[tau] = x[bb * T_ + t0 + tr];
    }
    __syncthreads();

    // gather A: 64 rows x 256 f32 -> fp16 LDS. 4 threads/row, 16 float4 each.
    {
        int r = tau >> 2, quarter = tau & 3;
        const float4* src =
            (const float4*)(embed + (size_t)tok_s[r] * D_ + quarter * 64);
        f16* dst = &A_s[r][quarter * 64];
#pragma unroll
        for (int j = 0; j < 16; j++) {
            float4 v = src[j];
            dst[j * 4 + 0] = (f16)v.x;
            dst[j * 4 + 1] = (f16)v.y;
            dst[j * 4 + 2] = (f16)v.z;
            dst[j * 4 + 3] = (f16)v.w;
        }
    }

    for (int np = 0; np < 8; np++) {
        f32x4 acc[8];
#pragma unroll
        for (int ni = 0; ni < 8; ni++) acc[ni] = (f32x4){0.f, 0.f, 0.f, 0.f};

        for (int kt = 0; kt < 4; kt++) {
            __syncthreads();  // previous B_s consumers done
            {
                int n = tau >> 1, half = tau & 1;
                const f16x8* src = (const f16x8*)(WxT +
                    (size_t)(np * 128 + n) * 256 + kt * 64 + half * 32);
                f16x8* dst = (f16x8*)&B_s[n][half * 32];
#pragma unroll
                for (int j = 0; j < 4; j++) dst[j] = src[j];
            }
            __syncthreads();
#pragma unroll
            for (int s = 0; s < 2; s++) {
                f16x8 afrag =
                    *(const f16x8*)&A_s[wave * 16 + c][kt * 64 + s * 32 + q * 8];
#pragma unroll
                for (int ni = 0; ni < 8; ni++) {
                    f16x8 bfrag = *(const f16x8*)&B_s[ni * 16 + c][s * 32 + q * 8];
                    acc[ni] = __builtin_amdgcn_mfma_f32_16x16x32_f16(
                        afrag, bfrag, acc[ni], 0, 0, 0);
                }
            }
        }
        // epilogue (half-split + gate-interleaved column write)
#pragma unroll
        for (int ni = 0; ni < 8; ni++) {
            int n    = np * 128 + ni * 16 + c;
            int g    = n >> 8, rem = n & 255;
            int half = rem >> 7, colu = rem & 127;
            int np2  = half * 512 + colu * 4 + g;
            float bv = bias[n];
#pragma unroll
            for (int r = 0; r < 4; r++) {
                int row = i0 + wave * 16 + q * 4 + r;
                Zx[(size_t)row * N4H + np2] = (f16)(acc[ni][r] + bv);
            }
        }
    }
}

// ===========================================================================
// Fused k3 launch: blocks 0..31 = LSTM; [32, 32+npz) = next-chunk Zx
// producer; [32+npz, ...) = prev-chunk vu producer (attention pre-pass).
// All share one LDS arena (union, 87040 B) so total LDS stays < 160 KiB.
// ===========================================================================
#define SMEM_BYTES 87040

// ---------------------------------------------------------------------------
// Zx producer, 512-thread variant of k2 (128 rows/block), for chunk t0n.
// ---------------------------------------------------------------------------
__device__ __forceinline__ void zx_producer(
    const int* __restrict__ x, const float* __restrict__ embed,
    const f16* __restrict__ WxT, const float* __restrict__ bias,
    f16* __restrict__ Zx, int pb, int t0, int Tc, char* smem) {
    f16 (*Ap_s)[264] = (f16(*)[264])smem;                  // 128*264*2=67584
    f16 (*Bp_s)[72]  = (f16(*)[72])(smem + 67584);         // 128*72*2 =18432
    int* tokp_s      = (int*)(smem + 86016);               // 512

    int tau  = threadIdx.x;           // 0..511
    int i0   = pb * 128;
    int wave = tau >> 6, lane = tau & 63;
    int q = lane >> 4, c = lane & 15;

    if (tau < 128) {
        int i  = i0 + tau;
        int bb = i / Tc, tr = i - bb * Tc;
        tokp_s[tau] = x[bb * T_ + t0 + tr];
    }
    __syncthreads();

    // gather A: 128 rows x 256 f32 -> fp16 LDS. 4 threads/row.
    {
        int r = tau >> 2, quarter = tau & 3;
        const float4* src =
            (const float4*)(embed + (size_t)tokp_s[r] * D_ + quarter * 64);
        f16* dst = &Ap_s[r][quarter * 64];
#pragma unroll
        for (int j = 0; j < 16; j++) {
            float4 v = src[j];
            dst[j * 4 + 0] = (f16)v.x;
            dst[j * 4 + 1] = (f16)v.y;
            dst[j * 4 + 2] = (f16)v.z;
            dst[j * 4 + 3] = (f16)v.w;
        }
    }

    for (int np = 0; np < 8; np++) {
        f32x4 acc[8];
#pragma unroll
        for (int ni = 0; ni < 8; ni++) acc[ni] = (f32x4){0.f, 0.f, 0.f, 0.f};

        for (int kt = 0; kt < 4; kt++) {
            __syncthreads();  // previous B_s consumers done (covers A_s fill)
            {
                int n = tau >> 2, qt = tau & 3;   // 128 n x 4 x 16 elems
                const f16x8* src = (const f16x8*)(WxT +
                    (size_t)(np * 128 + n) * 256 + kt * 64 + qt * 16);
                f16x8* dst = (f16x8*)&Bp_s[n][qt * 16];
                dst[0] = src[0];
                dst[1] = src[1];
            }
            __syncthreads();
#pragma unroll
            for (int s = 0; s < 2; s++) {
                f16x8 afrag =
                    *(const f16x8*)&Ap_s[wave * 16 + c][kt * 64 + s * 32 + q * 8];
#pragma unroll
                for (int ni = 0; ni < 8; ni++) {
                    f16x8 bfrag = *(const f16x8*)&Bp_s[ni * 16 + c][s * 32 + q * 8];
                    acc[ni] = __builtin_amdgcn_mfma_f32_16x16x32_f16(
                        afrag, bfrag, acc[ni], 0, 0, 0);
                }
            }
        }
#pragma unroll
        for (int ni = 0; ni < 8; ni++) {
            int n     = np * 128 + ni * 16 + c;
            int g     = n >> 8, rem = n & 255;
            int halfn = rem >> 7, colu = rem & 127;
            int np2   = halfn * 512 + colu * 4 + g;
            float bv  = bias[n];
#pragma unroll
            for (int r = 0; r < 4; r++) {
                int row = i0 + wave * 16 + q * 4 + r;
                Zx[(size_t)row * N4H + np2] = (f16)(acc[ni][r] + bv);
            }
        }
    }
}

// ---------------------------------------------------------------------------
// vu producer: attention pre-pass for one batch row b over chunk [t0v,t0v+Tc):
// vu[b][t] = tanh(outs[b][t][:] @ Womega + b_omega) . u_omega.
// Exactly k4's per-chapter math; only waves 0-3 (tau<256) do the work,
// waves 4-7 participate in barriers only. outs for this chunk was completed
// by the PREVIOUS k3 launch (stream-serialized), so no intra-launch race.
// ---------------------------------------------------------------------------
__device__ __forceinline__ void vu_producer(
    const f16* __restrict__ outs, const f16* __restrict__ WomT,
    const float* __restrict__ b_omega, const float* __restrict__ u_omega,
    float* __restrict__ vuout, int b, int t0v, int Tc, char* smem) {
    f16 (*A_s)[264]   = (f16(*)[264])smem;                 // 64*264*2=33792
    f16 (*val_s)[132] = (f16(*)[132])(smem + 33792);       // 64*132*2=16896
    float* u_s        = (float*)(smem + 50688);            // 512

    int tau  = threadIdx.x;           // 0..511
    int wave = tau >> 6, lane = tau & 63;
    int q = lane >> 4, c = lane & 15;

    if (tau < 128) u_s[tau] = u_omega[tau];
    float bom[8];
#pragma unroll
    for (int ni = 0; ni < 8; ni++) bom[ni] = b_omega[ni * 16 + c];

    int nchap = Tc >> 6;
    for (int ch = 0; ch < nchap; ch++) {
        int t0c = t0v + ch * 64;
        __syncthreads();  // A_s/val_s reuse (+ covers u_s init)
        if (tau < 256) {  // stage 64 rows of outs
            int r = tau >> 2, seg = tau & 3;
            const f16x8* src =
                (const f16x8*)(outs + ((size_t)b * T_ + t0c + r) * H_ + seg * 64);
            f16x8* dst = (f16x8*)&A_s[r][seg * 64];
#pragma unroll
            for (int j = 0; j < 8; j++) dst[j] = src[j];
        }
        __syncthreads();
        if (tau < 256) {
            f32x4 acc[8];
#pragma unroll
            for (int ni = 0; ni < 8; ni++) acc[ni] = (f32x4){0.f, 0.f, 0.f, 0.f};
#pragma unroll
            for (int kc = 0; kc < 8; kc++) {
                f16x8 afrag = *(const f16x8*)&A_s[wave * 16 + c][kc * 32 + q * 8];
#pragma unroll
                for (int ni = 0; ni < 8; ni++) {
                    f16x8 bfrag = *(const f16x8*)(WomT +
                        (size_t)(ni * 16 + c) * 256 + kc * 32 + q * 8);
                    acc[ni] = __builtin_amdgcn_mfma_f32_16x16x32_f16(
                        afrag, bfrag, acc[ni], 0, 0, 0);
                }
            }
#pragma unroll
            for (int ni = 0; ni < 8; ni++) {
#pragma unroll
                for (int r = 0; r < 4; r++) {
                    val_s[wave * 16 + q * 4 + r][ni * 16 + c] =
                        (f16)tanh_f(acc[ni][r] + bom[ni]);
                }
            }
        }
        __syncthreads();
        if (tau < 64) {
            float s = 0.f;
#pragma unroll 8
            for (int a = 0; a < 128; a++) s += (float)val_s[tau][a] * u_s[a];
            vuout[(size_t)b * T_ + t0c + tau] = s;
        }
    }
}

// ---------------------------------------------------------------------------
// K3: persistent LSTM, split-K pipelined pair exchange (verified structure,
// round-5 LSTM body untouched), fused with Zx producer + vu producer blocks.
// LSTM blocks are blockIdx 0..31 -> dispatched first -> resident first; the
// producer families have no inter-block sync, so no scheduling order can
// deadlock the pair spin (worst case is delay).
// ---------------------------------------------------------------------------
__global__ __launch_bounds__(512, 2) void k3_lstm(
    const f16* __restrict__ Zx, const f16* __restrict__ WhT,
    const int* __restrict__ seqlen, f16* __restrict__ outs,
    f16* __restrict__ Hstate, float* __restrict__ Cstate,
    u32* __restrict__ Hex, int t0, int Tc, int first, int last,
    const int* __restrict__ x, const float* __restrict__ embed,
    const f16* __restrict__ WxT, const float* __restrict__ bias,
    f16* __restrict__ ZxNext, int t0n, int npz,
    const f16* __restrict__ WomT, const float* __restrict__ b_omega,
    const float* __restrict__ u_omega, float* __restrict__ vuout, int t0v) {
    __shared__ __align__(16) char smem[SMEM_BYTES];  // union arena

    if (blockIdx.x >= 32) {
        int pid = blockIdx.x - 32;
        if (pid < npz)
            zx_producer(x, embed, WxT, bias, ZxNext, pid, t0n, Tc, smem);
        else
            vu_producer(outs, WomT, b_omega, u_omega, vuout, pid - npz, t0v,
                        Tc, smem);
        return;
    }

    f16 (*Zx_s)[16][520] = (f16(*)[16][520])smem;          // 2*16*520*2=33280
    f16 (*h_s)[16][264]  = (f16(*)[16][264])(smem + 33280); // 2*16*264*2=16896

    int tau  = threadIdx.x;
    int w    = tau >> 6, lane = tau & 63;
    int q = lane >> 4, c = lane & 15;
    int wgid = blockIdx.x;
    int pair = wgid >> 1, half = wgid & 1;
    int b0 = pair * 16;
    int u0 = half * 128, pu0 = (half ^ 1) * 128;
    int u  = u0 + w * 16 + c;   // this lane's hidden unit
    int col = w * 16 + c;       // unit index inside our 128-chunk

    u32* hexw_my = Hex + (size_t)wgid * 2 * 2048;        // [parity][16][128]
    u32* hexw_pr = Hex + (size_t)(wgid ^ 1) * 2 * 2048;

    // ---- Wh fragments pinned in AGPRs; slot s<4 = own-half K, s>=4 partner ----
    f32x4 wha[4][8];
#pragma unroll
    for (int g = 0; g < 4; g++)
#pragma unroll
        for (int s = 0; s < 8; s++) {
            int kc = (s < 4) ? (half * 4 + s) : ((half ^ 1) * 4 + (s - 4));
            f16x8 f = *(const f16x8*)(WhT +
                (size_t)(g * 256 + u0 + w * 16 + c) * 256 + kc * 32 + q * 8);
            f32x4 t = __builtin_bit_cast(f32x4, f);
            asm volatile("" : "=a"(wha[g][s]) : "0"(t));
        }

    // k-element offsets within an h_s row for the two K-halves
    int kOwn = half * 128 + q * 8;          // + kk*32
    int kPar = (half ^ 1) * 128 + q * 8;

    // ---- init h_s / cst / hprev ----
    int p0 = t0 & 1;
    if (first) {
        for (int idx = tau; idx < 2 * 16 * 264; idx += 512)
            ((f16*)h_s)[idx] = (f16)0.f;
    } else {
        for (int idx = tau; idx < 16 * 256; idx += 512) {
            int r = idx >> 8, k = idx & 255;
            h_s[p0][r][k] = Hstate[(b0 + r) * H_ + k];
        }
    }

    float cst[4];
    f16   hprev[4];
    int   sl[4];
#pragma unroll
    for (int r = 0; r < 4; r++) {
        int row = q * 4 + r;
        cst[r]   = first ? 0.f : Cstate[(b0 + row) * H_ + u];
        hprev[r] = first ? (f16)0.f : Hstate[(b0 + row) * H_ + u];
        sl[r]    = seqlen[b0 + row];
    }

    // Zx staging geometry: thread stages 32 B of row (tau>>5), cols (tau&31)*16
    int r_st = tau >> 5;
    int cc   = (tau & 31) * 16;
    const f16* zxrow = Zx + ((size_t)(b0 + r_st) * Tc) * N4H + half * 512 + cc;

    // prologue: fill Zx_s for step 0
    {
        const f16x8* src = (const f16x8*)zxrow;
        f16x8* dst = (f16x8*)&Zx_s[p0][r_st][cc];
        dst[0] = src[0];
        dst[1] = src[1];
    }
    // partner-merge geometry: thread handles 4 words: row tau>>5, cols (tau&31)*4
    int rr = tau >> 5;
    int uu = (tau & 31) * 4;

    __syncthreads();  // prologue: full drain once is fine

    // prologue: own-half partial MFMA from h_s[p0]
    f32x4 accO[4];
#pragma unroll
    for (int g = 0; g < 4; g++) accO[g] = (f32x4){0.f, 0.f, 0.f, 0.f};
#pragma unroll
    for (int kk = 0; kk < 4; kk++) {
        f16x8 afrag = *(const f16x8*)&h_s[p0][c][kOwn + kk * 32];
#pragma unroll
        for (int g = 0; g < 4; g++) MFMA_A(accO[g], afrag, wha[g][kk]);
    }

    u64 vp0 = 0, vp1 = 0;  // in-flight partner poll payload

    for (int tt = 0; tt < Tc; tt++) {
        int t   = t0 + tt;
        int cur = t & 1, nxt = cur ^ 1;

        // Zx prefetch for t+1 (max latency cover: consumed end of iteration)
        int tn = (tt + 1 < Tc) ? tt + 1 : tt;
        const f16x8* psrc = (const f16x8*)(zxrow + (size_t)tn * N4H);
        f16x8 z0 = psrc[0];
        f16x8 z1 = psrc[1];

        // poll + merge partner half of h_t (skip at chunk start: h_s complete)
        if (tt > 0) {
            u32 tagp = (u32)(t & 0xffff);
            const u64* pp = (const u64*)&hexw_pr[cur * 2048 + rr * 128 + uu];
            while (((u32)(vp0 >> 16) & 0xffffu) != tagp ||
                   ((u32)(vp0 >> 48)) != tagp ||
                   ((u32)(vp1 >> 16) & 0xffffu) != tagp ||
                   ((u32)(vp1 >> 48)) != tagp) {
                vp0 = __hip_atomic_load(pp + 0, __ATOMIC_RELAXED,
                                        __HIP_MEMORY_SCOPE_AGENT);
                vp1 = __hip_atomic_load(pp + 1, __ATOMIC_RELAXED,
                                        __HIP_MEMORY_SCOPE_AGENT);
            }
            u64 hw = (u64)(vp0 & 0xffff) | (((vp0 >> 32) & 0xffff) << 16) |
                     ((vp1 & 0xffff) << 32) | (((vp1 >> 32) & 0xffff) << 48);
            *(u64*)&h_s[cur][rr][pu0 + uu] = hw;
        }
        LGKM_BARRIER();  // partner half visible; h_s[cur] complete

        // partner-half K MFMA (slots 4-7) -> full pre-activations in accO
#pragma unroll
        for (int kk = 0; kk < 4; kk++) {
            f16x8 afrag = *(const f16x8*)&h_s[cur][c][kPar + kk * 32];
#pragma unroll
            for (int g = 0; g < 4; g++) MFMA_A(accO[g], afrag, wha[g][4 + kk]);
        }

        // gates (C layout: col=c, row=q*4+r); publish own h with tag t+1
        u32 tag = (u32)((t + 1) & 0xffff);
        f16 ovals[4];
#pragma unroll
        for (int r = 0; r < 4; r++) {
            int row = q * 4 + r;
            f16x4 zv = *(const f16x4*)&Zx_s[cur][row][col * 4];
            float zi = accO[0][r] + (float)zv[0];
            float zj = accO[1][r] + (float)zv[1];
            float zf = accO[2][r] + (float)zv[2];
            float zo = accO[3][r] + (float)zv[3];
            float ig = sigmoid_f(zi);
            float jg = tanh_f(zj);
            float fg = sigmoid_f(zf + 1.f);
            float og = sigmoid_f(zo);
            float cn = cst[r] * fg + ig * jg;
            float hn = tanh_f(cn) * og;
            bool  m  = (t < sl[r]);
            cst[r]   = m ? cn : cst[r];
            f16 hkeep = m ? (f16)hn : hprev[r];
            hprev[r]  = hkeep;
            h_s[nxt][row][u] = hkeep;
            u32 word = (tag << 16) |
                       (u32)(unsigned short)__builtin_bit_cast(short, hkeep);
            __hip_atomic_store(&hexw_my[nxt * 2048 + row * 128 + col], word,
                               __ATOMIC_RELAXED, __HIP_MEMORY_SCOPE_AGENT);
            ovals[r] = m ? (f16)hn : (f16)0.f;
        }

        // consume Zx prefetch into other parity
        {
            f16x8* dst = (f16x8*)&Zx_s[nxt][r_st][cc];
            dst[0] = z0;
            dst[1] = z1;
        }

        // outs stores
#pragma unroll
        for (int r = 0; r < 4; r++)
            outs[((size_t)(b0 + q * 4 + r) * T_ + t) * H_ + u] = ovals[r];

        // issue partner polls for h_{t+1} LAST: sample L3 late (past the
        // partner's publish-to-L3 latency); stay in flight across the barrier.
        {
            const u64* pp2 = (const u64*)&hexw_pr[nxt * 2048 + rr * 128 + uu];
            vp0 = __hip_atomic_load(pp2 + 0, __ATOMIC_RELAXED,
                                    __HIP_MEMORY_SCOPE_AGENT);
            vp1 = __hip_atomic_load(pp2 + 1, __ATOMIC_RELAXED,
                                    __HIP_MEMORY_SCOPE_AGENT);
        }

        LGKM_BARRIER();  // own half of h_s[nxt] + Zx_s[nxt] ready

        // own-half K MFMA for step t+1 (slots 0-3) — covers exchange RTT
#pragma unroll
        for (int g = 0; g < 4; g++) accO[g] = (f32x4){0.f, 0.f, 0.f, 0.f};
#pragma unroll
        for (int kk = 0; kk < 4; kk++) {
            f16x8 afrag = *(const f16x8*)&h_s[nxt][c][kOwn + kk * 32];
#pragma unroll
            for (int g = 0; g < 4; g++) MFMA_A(accO[g], afrag, wha[g][kk]);
        }
    }

    if (!last) {
        int parity = (t0 + Tc) & 1;
        for (int idx = tau; idx < 16 * 128; idx += 512) {
            int r = idx >> 7, k = u0 + (idx & 127);
            Hstate[(b0 + r) * H_ + k] = h_s[parity][r][k];
        }
#pragma unroll
        for (int r = 0; r < 4; r++)
            Cstate[(b0 + q * 4 + r) * H_ + u] = cst[r];
    }
}

// ---------------------------------------------------------------------------
// K4: attention + head. One WG (256 thr) per batch row.
// vu for t < tstart comes precomputed from the fused vu-producer blocks;
// only the last chunk's chapters are computed here.
// ---------------------------------------------------------------------------
__global__ __launch_bounds__(256) void k4_attn(
    const f16* __restrict__ outs, const f16* __restrict__ WomT,
    const float* __restrict__ b_omega, const float* __restrict__ u_omega,
    const float* __restrict__ w, const float* __restrict__ bfin,
    const float* __restrict__ vuin, int tstart, float* __restrict__ out) {
    __shared__ __align__(16) f16 A_s[64][264];
    __shared__ __align__(16) f16 val_s[64][132];
    __shared__ float u_s[128];
    __shared__ float vu_s[512];
    __shared__ float red0[256], red1[256];

    int b = blockIdx.x, tau = threadIdx.x;
    int wave = tau >> 6, lane = tau & 63;
    int q = lane >> 4, c = lane & 15;

    if (tau < 128) u_s[tau] = u_omega[tau];
    float bom[8];
#pragma unroll
    for (int ni = 0; ni < 8; ni++) bom[ni] = b_omega[ni * 16 + c];

    // fill precomputed vu (tstart is a multiple of 64; 0 disables)
    for (int t = tau; t < tstart; t += 256) vu_s[t] = vuin[(size_t)b * T_ + t];

    for (int ch = tstart >> 6; ch < 8; ch++) {
        int t0c = ch * 64;
        __syncthreads();  // protects A_s/val_s reuse (+ covers u_s/vu fill)
        {   // stage 64 rows of outs
            int r = tau >> 2, seg = tau & 3;
            const f16x8* src =
                (const f16x8*)(outs + ((size_t)b * T_ + t0c + r) * H_ + seg * 64);
            f16x8* dst = (f16x8*)&A_s[r][seg * 64];
#pragma unroll
            for (int j = 0; j < 8; j++) dst[j] = src[j];
        }
        __syncthreads();

        f32x4 acc[8];
#pragma unroll
        for (int ni = 0; ni < 8; ni++) acc[ni] = (f32x4){0.f, 0.f, 0.f, 0.f};
#pragma unroll
        for (int kc = 0; kc < 8; kc++) {
            f16x8 afrag = *(const f16x8*)&A_s[wave * 16 + c][kc * 32 + q * 8];
#pragma unroll
            for (int ni = 0; ni < 8; ni++) {
                f16x8 bfrag = *(const f16x8*)(WomT +
                    (size_t)(ni * 16 + c) * 256 + kc * 32 + q * 8);
                acc[ni] = __builtin_amdgcn_mfma_f32_16x16x32_f16(
                    afrag, bfrag, acc[ni], 0, 0, 0);
            }
        }
#pragma unroll
        for (int ni = 0; ni < 8; ni++) {
#pragma unroll
            for (int r = 0; r < 4; r++) {
                val_s[wave * 16 + q * 4 + r][ni * 16 + c] =
                    (f16)tanh_f(acc[ni][r] + bom[ni]);
            }
        }
        __syncthreads();
        if (tau < 64) {
            float s = 0.f;
#pragma unroll 8
            for (int a = 0; a < 128; a++) s += (float)val_s[tau][a] * u_s[a];
            vu_s[t0c + tau] = s;
        }
    }
    __syncthreads();

    // softmax over T=512
    red0[tau] = fmaxf(vu_s[tau], vu_s[tau + 256]);
    __syncthreads();
    for (int s = 128; s > 0; s >>= 1) {
        if (tau < s) red0[tau] = fmaxf(red0[tau], red0[tau + s]);
        __syncthreads();
    }
    float mx = red0[0];
    __syncthreads();
    float e0 = __expf(vu_s[tau] - mx), e1 = __expf(vu_s[tau + 256] - mx);
    red0[tau] = e0 + e1;
    __syncthreads();
    for (int s = 128; s > 0; s >>= 1) {
        if (tau < s) red0[tau] += red0[tau + s];
        __syncthreads();
    }
    float inv = 1.f / red0[0];
    __syncthreads();
    vu_s[tau]       = e0 * inv;
    vu_s[tau + 256] = e1 * inv;
    __syncthreads();

    // last[h] = sum_t alpha[t] * outs[b][t][h]   (tau = h)
    float lastv = 0.f;
#pragma unroll 4
    for (int t = 0; t < T_; t++)
        lastv += vu_s[t] * (float)outs[((size_t)b * T_ + t) * H_ + tau];

    // logits + 2-class softmax
    red0[tau] = lastv * w[tau * 2 + 0];
    red1[tau] = lastv * w[tau * 2 + 1];
    __syncthreads();
    for (int s = 128; s > 0; s >>= 1) {
        if (tau < s) {
            red0[tau] += red0[tau + s];
            red1[tau] += red1[tau + s];
        }
        __syncthreads();
    }
    if (tau == 0) {
        float l0 = red0[0] + bfin[0], l1 = red1[0] + bfin[1];
        float mm = fmaxf(l0, l1);
        float a0 = __expf(l0 - mm), a1 = __expf(l1 - mm);
        float den = a0 + a1;
        out[b * 2 + 0] = a0 / den;
        out[b * 2 + 1] = a1 / den;
    }
}

// ---------------------------------------------------------------------------
extern "C" void kernel_launch(void* const* d_in, const int* in_sizes, int n_in,
                              void* d_out, int out_size, void* d_ws,
                              size_t ws_size, hipStream_t stream) {
    const int*   x           = (const int*)d_in[0];
    const float* embed       = (const float*)d_in[1];
    const float* lstm_kernel = (const float*)d_in[2];
    const float* lstm_bias   = (const float*)d_in[3];
    const float* w_omega     = (const float*)d_in[4];
    const float* b_omega     = (const float*)d_in[5];
    const float* u_omega     = (const float*)d_in[6];
    const float* w           = (const float*)d_in[7];
    const float* bfin        = (const float*)d_in[8];
    float*       out         = (float*)d_out;

    char* ws = (char*)d_ws;
    f16*   WxT    = (f16*)(ws + 0);              //  524288 B
    f16*   WhT    = (f16*)(ws + 524288);         //  524288 B
    f16*   WomT   = (f16*)(ws + 1048576);        //   65536 B
    int*   seqlen = (int*)(ws + 1114112);        //    1024 B
    f16*   Hstate = (f16*)(ws + 1115136);        //  131072 B
    float* Cstate = (float*)(ws + 1246208);      //  262144 B
    u32*   Hex    = (u32*)(ws + 1508352);        //  524288 B (32 wg x 2 x 8KB)
    float* vu     = (float*)(ws + 2032640);      //  524288 B (B x T f32)
    f16*   outs   = (f16*)(ws + 2556928);        // 67108864 B

    // Zx double buffer for producer-fusion: need fixed + 2 chunks <= ws.
    const size_t fixed = 2556928ull + 67108864ull;
    int nch = 1;
    while (nch < 16 && fixed + 2ull * (268435456ull / (size_t)nch) > ws_size)
        nch <<= 1;
    int Tc = T_ / nch;
    size_t chunkB = 268435456ull / (size_t)nch;
    f16* ZxA = (f16*)(ws + fixed);
    f16* ZxB = (f16*)(ws + fixed + chunkB);  // unused when nch == 1

    // vu fusion requires chunk length a multiple of the 64-step chapter size
    int vuEnable = (Tc % 64 == 0) && (nch >= 2);
    int tstart   = vuEnable ? (nch - 1) * Tc : 0;

    k0_convert<<<1152, 256, 0, stream>>>(lstm_kernel, w_omega, WxT, WhT, WomT);
    k1_seqlen<<<256, 256, 0, stream>>>(x, seqlen);
    // chunk 0's Zx is the only one computed standalone
    k2_zx<<<(B_ * Tc) / 64, 256, 0, stream>>>(x, embed, WxT, lstm_bias, ZxA,
                                              0, Tc);
    for (int chk = 0; chk < nch; chk++) {
        int  t0  = chk * Tc;
        f16* zc  = (chk & 1) ? ZxB : ZxA;
        f16* zn  = (chk & 1) ? ZxA : ZxB;
        int  npz = (chk + 1 < nch) ? (B_ * Tc) / 128 : 0;  // Zx producer blocks
        int  nv  = (vuEnable && chk >= 1) ? B_ : 0;        // vu producer blocks
        int  t0n = (chk + 1) * Tc;
        int  t0v = (chk - 1) * Tc;
        k3_lstm<<<32 + npz + nv, 512, 0, stream>>>(
            zc, WhT, seqlen, outs, Hstate, Cstate, Hex, t0, Tc,
            chk == 0 ? 1 : 0, chk == nch - 1 ? 1 : 0,
            x, embed, WxT, lstm_bias, zn, t0n, npz,
            WomT, b_omega, u_omega, vu, t0v);
    }
    k4_attn<<<256, 256, 0, stream>>>(outs, WomT, b_omega, u_omega, w, bfin,
                                     vu, tstart, out);
}